// Round 9
// baseline (608.646 us; speedup 1.0000x reference)
//
#include <hip/hip_runtime.h>

#define N_NODESC 20000
#define N_EDGESC 320000
#define HC 640
#define NGRAPH 500

typedef unsigned short u16;
typedef unsigned int u32;
typedef __attribute__((ext_vector_type(8))) short bf16x8;
typedef __attribute__((ext_vector_type(4))) float f32x4;

__device__ __forceinline__ float wred_sum(float v){
  #pragma unroll
  for(int o=32;o;o>>=1) v += __shfl_xor(v,o,64);
  return v;
}
__device__ __forceinline__ float wred_max(float v){
  #pragma unroll
  for(int o=32;o;o>>=1) v = fmaxf(v,__shfl_xor(v,o,64));
  return v;
}
__device__ __forceinline__ float lrelu(float x){ return x>0.f? x:0.2f*x; }

__device__ __forceinline__ u16 f2bf(float f){
  u32 u=__float_as_uint(f);
  u32 r=u+0x7FFFu+((u>>16)&1u);
  return (u16)(r>>16);
}
__device__ __forceinline__ float bf2f(u16 s){ return __uint_as_float(((u32)s)<<16); }
__device__ __forceinline__ float bflo(u32 w){ return __uint_as_float(w<<16); }
__device__ __forceinline__ float bfhi(u32 w){ return __uint_as_float(w&0xFFFF0000u); }

__device__ __forceinline__ void gload16(const void* g, void* l){
  __builtin_amdgcn_global_load_lds((const __attribute__((address_space(1))) void*)g,
                                   (__attribute__((address_space(3))) void*)l, 16, 0, 0);
}

// ---------------- graph preprocessing (layer-invariant) ----------------

__global__ void k_count(const int* __restrict__ dst, int* __restrict__ cnt){
  int i=blockIdx.x*blockDim.x+threadIdx.x;
  if(i>=N_EDGESC) return;
  atomicAdd(&cnt[dst[i]],1);
}

__global__ void k_scan(const int* __restrict__ cnt, int* __restrict__ rptr, int* __restrict__ pos){
  __shared__ int ps[1024];
  int t=threadIdx.x;
  const int CH=20;
  int beg=t*CH, end=min(beg+CH, N_NODESC);
  int s=0;
  for(int i=beg;i<end;i++) s+=cnt[i];
  ps[t]=s; __syncthreads();
  for(int off=1;off<1024;off<<=1){
    int v=(t>=off)? ps[t-off]:0;
    __syncthreads();
    ps[t]+=v;
    __syncthreads();
  }
  int base=ps[t]-s;
  for(int i=beg;i<end;i++){ rptr[i]=base; pos[i]=base; base+=cnt[i]; }
}

__global__ void k_scatter(const int* __restrict__ dst, int* __restrict__ pos, int* __restrict__ eidx){
  int i=blockIdx.x*blockDim.x+threadIdx.x;
  if(i>=N_EDGESC) return;
  int j=atomicAdd(&pos[dst[i]],1);
  eidx[j]=i;
}

// scatter-mean of edge_attr per dst node via CSR (no atomics); one wave per node
__global__ __launch_bounds__(256) void k_loop_attr(const float* __restrict__ eattr,
    const int* __restrict__ rptr, const int* __restrict__ cnt, const int* __restrict__ eidx,
    float* __restrict__ lattr){
  int tid=threadIdx.x, lane=tid&63;
  int n=blockIdx.x*4+(tid>>6);
  if(n>=N_NODESC) return;
  int beg=rptr[n], deg=cnt[n];
  float s[10]={0,0,0,0,0,0,0,0,0,0};
  for(int off=lane; off<deg; off+=64){
    int e=eidx[beg+off];
    const float* ep=&eattr[(size_t)e*10];
    #pragma unroll
    for(int k=0;k<10;k++) s[k]+=ep[k];
  }
  float inv=1.f/fmaxf((float)deg,1.f);
  #pragma unroll
  for(int k=0;k<10;k++){
    float tot=wred_sum(s[k]);
    if(lane==0) lattr[(size_t)n*10+k]=tot*inv;
  }
}

// ---------------- conversions ----------------

__global__ void k_conv_x(const float* __restrict__ x, u16* __restrict__ hi, u16* __restrict__ lo){
  int idx=blockIdx.x*blockDim.x+threadIdx.x;
  if(idx>=N_NODESC*64) return;
  int n=idx>>6, kk=idx&63;
  float v = kk<43 ? x[n*43+kk] : 0.f;
  u16 h=f2bf(v);
  hi[idx]=h; lo[idx]=f2bf(v-bf2f(h));
}

__global__ void k_conv_w(const float* __restrict__ W, u16* __restrict__ hi, u16* __restrict__ lo,
                         int KL, int KP){
  int idx=blockIdx.x*blockDim.x+threadIdx.x;
  if(idx>=HC*KP) return;
  int kk=idx/HC;
  int n=idx-kk*HC;
  float v = kk<KL ? W[(size_t)kk*HC+n] : 0.f;
  u16 h=f2bf(v);
  hi[(size_t)n*KP+kk]=h;
  lo[(size_t)n*KP+kk]=f2bf(v-bf2f(h));
}

// ---------------- per-layer kernels ----------------

__global__ void k_ve(const float* __restrict__ We, const float* __restrict__ aedge,
                     float* __restrict__ ve){
  int t=threadIdx.x;
  if(t>=50) return;
  int k=t/5, h=t%5;
  float s=0.f;
  for(int c=0;c<128;c++) s += We[k*HC + h*128 + c]*aedge[h*128+c];
  ve[k*5+h]=s;
}

// ael[n][h] = lattr[n,:] . ve[:,h]
__global__ void k_ael(const float* __restrict__ lattr, const float* __restrict__ ve,
                      float* __restrict__ ael){
  int idx=blockIdx.x*blockDim.x+threadIdx.x;
  if(idx>=N_NODESC*5) return;
  int n=idx/5, h=idx-5*n;
  float s=0.f;
  #pragma unroll
  for(int k=0;k<10;k++) s+=lattr[(size_t)n*10+k]*ve[k*5+h];
  ael[idx]=s;
}

// Fused GEMM + nodeatt: writes permuted bf16 hb + per-head al/ar.
// NT=3: C=Ahi@Bhi+Alo@Bhi+Ahi@Blo (layer 0). NT=2: C=A@Bhi+A@Blo.
// BK=32, DOUBLE-BUFFERED LDS (T3-minimal 2-phase): stage next tile before
// computing current; one barrier per K-step. NT=2: 48 KiB -> 3 blocks/CU.
// 128x128 tile, 4 waves each 64x64, XCD-bijective swizzle.
template<int NT>
__global__ __launch_bounds__(256,3) void k_gemm_fused(
    const u16* __restrict__ Ahi, const u16* __restrict__ Alo,
    const u16* __restrict__ Bhi, const u16* __restrict__ Blo,
    const float* __restrict__ asrc, const float* __restrict__ adst,
    u16* __restrict__ hb, float* __restrict__ al, float* __restrict__ ar,
    int M, int KP, int nblk){
  constexpr int TERMS=(NT==3)?4:3;
  constexpr int BOFF =(NT==3)?8192:4096;     // B-hi offset within buffer
  __shared__ u16 lds[2*TERMS*4096];
  int tid=threadIdx.x;
  int lane=tid&63;
  int w=tid>>6;
  int l15=lane&15, lg=lane>>4;
  // XCD-bijective swizzle: contiguous wg chunks per XCD
  int orig=blockIdx.x;
  int q=nblk>>3, r=nblk&7;
  int xcd=orig&7, off=orig>>3;
  int wg=(xcd<r? xcd*(q+1) : r*(q+1)+(xcd-r)*q)+off;
  int by=wg/5, bx=wg-5*by;
  int row0=by*128, col0=bx*128;
  int wr=w>>1, wc=w&1;

  f32x4 zero = {0.f,0.f,0.f,0.f};
  f32x4 acc[4][4];
  #pragma unroll
  for(int i=0;i<4;i++)
    #pragma unroll
    for(int j=0;j<4;j++) acc[i][j]=zero;

  auto stage=[&](int b, int k0){
    u16* base = lds + b*TERMS*4096;
    #pragma unroll
    for(int c=0;c<2;c++){
      int sb=w+4*c;                          // 8 sub-blocks of 16 rows x 32 k
      int col=k0+lg*8;
      size_t aoff=(size_t)(row0+sb*16+l15)*KP + col;
      size_t boff=(size_t)(col0+sb*16+l15)*KP + col;
      gload16(Ahi+aoff, base + sb*512);
      if constexpr(NT==3) gload16(Alo+aoff, base+4096 + sb*512);
      gload16(Bhi+boff, base+BOFF + sb*512);
      gload16(Blo+boff, base+BOFF+4096 + sb*512);
    }
  };

  int nt=KP/32;
  stage(0,0);
  __syncthreads();
  int cur=0;
  for(int t=0;t<nt;t++){
    if(t+1<nt) stage(cur^1,(t+1)*32);
    u16* cb = lds + cur*TERMS*4096;
    bf16x8 ah[4], bh[4], bl[4];
    #pragma unroll
    for(int i=0;i<4;i++){
      ah[i]=*(const bf16x8*)&cb[(wr*4+i)*512 + lane*8];
      bh[i]=*(const bf16x8*)&cb[BOFF+(wc*4+i)*512 + lane*8];
      bl[i]=*(const bf16x8*)&cb[BOFF+4096+(wc*4+i)*512 + lane*8];
    }
    if constexpr(NT==3){
      bf16x8 alv[4];
      #pragma unroll
      for(int i=0;i<4;i++) alv[i]=*(const bf16x8*)&cb[4096+(wr*4+i)*512+lane*8];
      #pragma unroll
      for(int i=0;i<4;i++)
        #pragma unroll
        for(int j=0;j<4;j++){
          acc[i][j]=__builtin_amdgcn_mfma_f32_16x16x32_bf16(ah[i], bh[j],acc[i][j],0,0,0);
          acc[i][j]=__builtin_amdgcn_mfma_f32_16x16x32_bf16(alv[i],bh[j],acc[i][j],0,0,0);
          acc[i][j]=__builtin_amdgcn_mfma_f32_16x16x32_bf16(ah[i], bl[j],acc[i][j],0,0,0);
        }
    }else{
      #pragma unroll
      for(int i=0;i<4;i++)
        #pragma unroll
        for(int j=0;j<4;j++){
          acc[i][j]=__builtin_amdgcn_mfma_f32_16x16x32_bf16(ah[i],bh[j],acc[i][j],0,0,0);
          acc[i][j]=__builtin_amdgcn_mfma_f32_16x16x32_bf16(ah[i],bl[j],acc[i][j],0,0,0);
        }
    }
    __syncthreads();
    cur^=1;
  }

  // ---- epilogue: hb (permuted bf16) + al/ar for head bx ----
  float asv[4], adv[4];
  #pragma unroll
  for(int j=0;j<4;j++){
    int c=col0+wc*64+j*16+l15;
    asv[j]=asrc[c]; adv[j]=adst[c];
  }
  // hb[n*640 + (c&63)*10 + (c>>6)] ; c&63 = j*16+l15 ; c>>6 = bx*2+wc
  #pragma unroll
  for(int i=0;i<4;i++){
    #pragma unroll
    for(int j=0;j<4;j++){
      #pragma unroll
      for(int rr=0;rr<4;rr++){
        int row=row0+wr*64+i*16+lg*4+rr;
        if(row<M) hb[(size_t)row*HC + (j*16+l15)*10 + bx*2+wc]=f2bf(acc[i][j][rr]);
      }
    }
  }
  // per-row partial dot over this wave's 64 cols, reduce across l15
  float* redAl=(float*)lds;       // 512 floats scratch
  float* redAr=redAl+256;
  #pragma unroll
  for(int i=0;i<4;i++){
    #pragma unroll
    for(int rr=0;rr<4;rr++){
      float sa=0.f, sd=0.f;
      #pragma unroll
      for(int j=0;j<4;j++){ sa+=acc[i][j][rr]*asv[j]; sd+=acc[i][j][rr]*adv[j]; }
      #pragma unroll
      for(int o=1;o<16;o<<=1){ sa+=__shfl_xor(sa,o,64); sd+=__shfl_xor(sd,o,64); }
      if(l15==0){
        int lr=wr*64+i*16+lg*4+rr;
        redAl[lr*2+wc]=sa; redAr[lr*2+wc]=sd;
      }
    }
  }
  __syncthreads();
  if(tid<128){
    int row=row0+tid;
    if(row<M){
      al[(size_t)row*5+bx]=redAl[tid*2]+redAl[tid*2+1];
      ar[(size_t)row*5+bx]=redAr[tid*2]+redAr[tid*2+1];
    }
  }
}

__global__ void k_ae(const float* __restrict__ eattr, const float* __restrict__ ve,
                     float* __restrict__ ae){
  __shared__ float ves[50];
  if(threadIdx.x<50) ves[threadIdx.x]=ve[threadIdx.x];
  __syncthreads();
  int i=blockIdx.x*blockDim.x+threadIdx.x;
  if(i>=N_EDGESC) return;
  float ev[10];
  #pragma unroll
  for(int k=0;k<10;k++) ev[k]=eattr[i*10+k];
  #pragma unroll
  for(int hh=0;hh<5;hh++){
    float s=0.f;
    #pragma unroll
    for(int k=0;k<10;k++) s+=ev[k]*ves[k*5+hh];
    ae[(size_t)i*5+hh]=s;
  }
}

// fused segment-softmax + aggregation; one wave per node. Gathers bf16 hb rows
// with a 4-deep unrolled inner loop (4 rows in flight).
// WBF: write bf16 (next layer GEMM A input). else: write f32 out.
template<bool RELU, bool WBF>
__global__ __launch_bounds__(256) void k_agg(const u16* __restrict__ hb, const int* __restrict__ src,
    const int* __restrict__ rptr, const int* __restrict__ cnt, const int* __restrict__ eidx,
    const float* __restrict__ al, const float* __restrict__ ar, const float* __restrict__ ael,
    const float* __restrict__ ae, const float* __restrict__ bias,
    float* __restrict__ out, u16* __restrict__ ohi){
  int tid=threadIdx.x, lane=tid&63;
  int n=blockIdx.x*4+(tid>>6);
  if(n>=N_NODESC) return;
  float arn[5], m[5], den[5], acc[10];
  #pragma unroll
  for(int hh=0;hh<5;hh++) arn[hh]=ar[n*5+hh];
  #pragma unroll
  for(int hh=0;hh<5;hh++){
    m[hh]=lrelu(al[n*5+hh]+arn[hh]+ael[n*5+hh]);
    den[hh]=1.f;
  }
  {
    const u32* sp=(const u32*)(hb+(size_t)n*HC+lane*10);
    #pragma unroll
    for(int j2=0;j2<5;j2++){
      u32 wv=sp[j2];
      acc[2*j2]  =bflo(wv);
      acc[2*j2+1]=bfhi(wv);
    }
  }
  int beg=rptr[n], deg=cnt[n];
  for(int off0=0; off0<deg; off0+=64){
    int c=min(64,deg-off0);
    bool valid = lane<c;
    int s=0; float p[5];
    #pragma unroll
    for(int hh=0;hh<5;hh++) p[hh]=-1e30f;
    if(valid){
      int e=eidx[beg+off0+lane];
      s=src[e];
      #pragma unroll
      for(int hh=0;hh<5;hh++) p[hh]=lrelu(al[s*5+hh]+arn[hh]+ae[(size_t)e*5+hh]);
    }
    float sc[5];
    #pragma unroll
    for(int hh=0;hh<5;hh++){
      float cm=wred_max(p[hh]);
      float nm=fmaxf(m[hh],cm);
      sc[hh]=__expf(m[hh]-nm);
      den[hh]*=sc[hh];
      float pv = valid? __expf(p[hh]-nm) : 0.f;
      p[hh]=pv;
      den[hh]+=wred_sum(pv);
      m[hh]=nm;
    }
    #pragma unroll
    for(int k=0;k<10;k++) acc[k]*=sc[k>>1];
    int j=0;
    for(; j+3<c; j+=4){
      int sjv[4];
      float pjv[4][5];
      u32 wv[4][5];
      #pragma unroll
      for(int u=0;u<4;u++) sjv[u]=__shfl(s,j+u,64);
      #pragma unroll
      for(int u=0;u<4;u++)
        #pragma unroll
        for(int hh=0;hh<5;hh++) pjv[u][hh]=__shfl(p[hh],j+u,64);
      #pragma unroll
      for(int u=0;u<4;u++){
        const u32* hr=(const u32*)(hb+(size_t)sjv[u]*HC+lane*10);
        #pragma unroll
        for(int j2=0;j2<5;j2++) wv[u][j2]=hr[j2];
      }
      #pragma unroll
      for(int u=0;u<4;u++)
        #pragma unroll
        for(int j2=0;j2<5;j2++){
          acc[2*j2]  +=pjv[u][j2]*bflo(wv[u][j2]);
          acc[2*j2+1]+=pjv[u][j2]*bfhi(wv[u][j2]);
        }
    }
    for(; j<c; j++){
      int sj=__shfl(s,j,64);
      float pj[5];
      #pragma unroll
      for(int hh=0;hh<5;hh++) pj[hh]=__shfl(p[hh],j,64);
      const u32* hr=(const u32*)(hb+(size_t)sj*HC+lane*10);
      #pragma unroll
      for(int j2=0;j2<5;j2++){
        u32 wv=hr[j2];
        acc[2*j2]  +=pj[j2]*bflo(wv);
        acc[2*j2+1]+=pj[j2]*bfhi(wv);
      }
    }
  }
  #pragma unroll
  for(int k=0;k<10;k++){
    int ccol=lane+64*k;
    float v=acc[k]/(den[k>>1]+1e-16f)+bias[ccol];
    if(RELU) v=fmaxf(v,0.f);
    if(WBF){
      ohi[(size_t)n*HC+ccol]=f2bf(v);
    }else{
      out[(size_t)n*HC+ccol]=v;
    }
  }
}

// ---------------- pooling + head ----------------

__global__ __launch_bounds__(256) void k_pool(const float* __restrict__ h, const float* __restrict__ wlin,
    const int* __restrict__ batch, float* __restrict__ ysum, float* __restrict__ cntg){
  int tid=threadIdx.x, lane=tid&63;
  int n=blockIdx.x*4+(tid>>6);
  if(n>=N_NODESC) return;
  float s=0.f;
  #pragma unroll
  for(int k=0;k<10;k++){ int c=lane+64*k; s+=h[(size_t)n*HC+c]*wlin[c]; }
  s=wred_sum(s);
  if(lane==0){
    int g=batch[n];
    atomicAdd(&ysum[g],s);
    atomicAdd(&cntg[g],1.f);
  }
}

__global__ void k_final(const float* __restrict__ ysum, const float* __restrict__ cntg,
                        const float* __restrict__ blin, float* __restrict__ out){
  int g=blockIdx.x*blockDim.x+threadIdx.x;
  if(g>=NGRAPH) return;
  out[g]=ysum[g]/fmaxf(cntg[g],1.f)+blin[0];
}

// ---------------- launch ----------------

extern "C" void kernel_launch(void* const* d_in, const int* in_sizes, int n_in,
                              void* d_out, int out_size, void* d_ws, size_t ws_size,
                              hipStream_t stream){
  const float* x     = (const float*)d_in[0];
  const float* eattr = (const float*)d_in[1];
  const float* W[3]    ={(const float*)d_in[2],(const float*)d_in[8],(const float*)d_in[14]};
  const float* We[3]   ={(const float*)d_in[3],(const float*)d_in[9],(const float*)d_in[15]};
  const float* asrc[3] ={(const float*)d_in[4],(const float*)d_in[10],(const float*)d_in[16]};
  const float* adst[3] ={(const float*)d_in[5],(const float*)d_in[11],(const float*)d_in[17]};
  const float* aedge[3]={(const float*)d_in[6],(const float*)d_in[12],(const float*)d_in[18]};
  const float* bias[3] ={(const float*)d_in[7],(const float*)d_in[13],(const float*)d_in[19]};
  const float* Wlin  = (const float*)d_in[20];
  const float* blin  = (const float*)d_in[21];
  const int* eind    = (const int*)d_in[22];
  const int* srcp    = eind;
  const int* dstp    = eind + N_EDGESC;
  const int* batch   = (const int*)d_in[23];
  float* out = (float*)d_out;

  char* ws=(char*)d_ws;
  size_t o=0;
  auto alloc=[&](size_t bytes)->void*{ void* p=ws+o; o=(o+bytes+255)&~(size_t)255; return p; };
  u16* hb   =(u16*)alloc((size_t)N_NODESC*HC*2);           // permuted bf16 h
  float* aggf =(float*)alloc((size_t)N_NODESC*HC*4);       // final layer f32 out
  u16* Ahi =(u16*)alloc((size_t)N_NODESC*HC*2);            // agg bf16 out (next GEMM A)
  u16* Axhi=(u16*)alloc((size_t)N_NODESC*64*2);            // converted x (KP=64)
  u16* Axlo=(u16*)alloc((size_t)N_NODESC*64*2);
  u16* Bthi=(u16*)alloc((size_t)HC*HC*2);                  // transposed weights
  u16* Btlo=(u16*)alloc((size_t)HC*HC*2);
  float* al   =(float*)alloc((size_t)N_NODESC*5*4);
  float* ar   =(float*)alloc((size_t)N_NODESC*5*4);
  float* ael  =(float*)alloc((size_t)N_NODESC*5*4);
  float* ae   =(float*)alloc((size_t)N_EDGESC*5*4);
  float* lattr=(float*)alloc((size_t)N_NODESC*10*4);
  float* ve   =(float*)alloc(64*4);
  float* ysum =(float*)alloc(512*4);
  float* cntg =(float*)alloc(512*4);
  int* cntI   =(int*)alloc((size_t)N_NODESC*4);
  int* rptr   =(int*)alloc((size_t)N_NODESC*4);
  int* pos    =(int*)alloc((size_t)N_NODESC*4);
  int* eidx   =(int*)alloc((size_t)N_EDGESC*4);

  hipMemsetAsync(cntI,0,(size_t)N_NODESC*4,stream);
  hipMemsetAsync(ysum,0,512*4,stream);
  hipMemsetAsync(cntg,0,512*4,stream);

  k_count<<<(N_EDGESC+255)/256,256,0,stream>>>(dstp,cntI);
  k_scan<<<1,1024,0,stream>>>(cntI,rptr,pos);
  k_scatter<<<(N_EDGESC+255)/256,256,0,stream>>>(dstp,pos,eidx);
  k_loop_attr<<<(N_NODESC+3)/4,256,0,stream>>>(eattr,rptr,cntI,eidx,lattr);
  k_conv_x<<<(N_NODESC*64+255)/256,256,0,stream>>>(x,Axhi,Axlo);

  const int NBLK=5*((N_NODESC+127)/128);
  for(int L=0;L<3;L++){
    int KL = (L==0)? 43 : HC;
    int KP = (L==0)? 64 : HC;
    k_ve<<<1,64,0,stream>>>(We[L],aedge[L],ve);
    k_conv_w<<<(HC*KP+255)/256,256,0,stream>>>(W[L],Bthi,Btlo,KL,KP);
    if(L==0)
      k_gemm_fused<3><<<NBLK,256,0,stream>>>(Axhi,Axlo,Bthi,Btlo,asrc[L],adst[L],hb,al,ar,N_NODESC,KP,NBLK);
    else
      k_gemm_fused<2><<<NBLK,256,0,stream>>>(Ahi,(const u16*)nullptr,Bthi,Btlo,asrc[L],adst[L],hb,al,ar,N_NODESC,KP,NBLK);
    k_ael<<<(N_NODESC*5+255)/256,256,0,stream>>>(lattr,ve,ael);
    k_ae<<<(N_EDGESC+255)/256,256,0,stream>>>(eattr,ve,ae);
    if(L<2)
      k_agg<true ,true ><<<(N_NODESC+3)/4,256,0,stream>>>(hb,srcp,rptr,cntI,eidx,al,ar,ael,ae,bias[L],aggf,Ahi);
    else
      k_agg<false,false><<<(N_NODESC+3)/4,256,0,stream>>>(hb,srcp,rptr,cntI,eidx,al,ar,ael,ae,bias[L],aggf,Ahi);
  }
  k_pool<<<(N_NODESC+3)/4,256,0,stream>>>(aggf,Wlin,batch,ysum,cntg);
  k_final<<<2,256,0,stream>>>(ysum,cntg,blin,out);
}

// Round 10
// 583.321 us; speedup vs baseline: 1.0434x; 1.0434x over previous
//
#include <hip/hip_runtime.h>

#define N_NODESC 20000
#define N_EDGESC 320000
#define HC 640
#define NGRAPH 500

typedef unsigned short u16;
typedef unsigned int u32;
typedef __attribute__((ext_vector_type(8))) short bf16x8;
typedef __attribute__((ext_vector_type(4))) float f32x4;

__device__ __forceinline__ float wred_sum(float v){
  #pragma unroll
  for(int o=32;o;o>>=1) v += __shfl_xor(v,o,64);
  return v;
}
__device__ __forceinline__ float wred_max(float v){
  #pragma unroll
  for(int o=32;o;o>>=1) v = fmaxf(v,__shfl_xor(v,o,64));
  return v;
}
__device__ __forceinline__ float lrelu(float x){ return x>0.f? x:0.2f*x; }

__device__ __forceinline__ u16 f2bf(float f){
  u32 u=__float_as_uint(f);
  u32 r=u+0x7FFFu+((u>>16)&1u);
  return (u16)(r>>16);
}
__device__ __forceinline__ float bf2f(u16 s){ return __uint_as_float(((u32)s)<<16); }
__device__ __forceinline__ float bflo(u32 w){ return __uint_as_float(w<<16); }
__device__ __forceinline__ float bfhi(u32 w){ return __uint_as_float(w&0xFFFF0000u); }

__device__ __forceinline__ void gload16(const void* g, void* l){
  __builtin_amdgcn_global_load_lds((const __attribute__((address_space(1))) void*)g,
                                   (__attribute__((address_space(3))) void*)l, 16, 0, 0);
}

// ---------------- graph preprocessing (layer-invariant) ----------------

__global__ void k_count(const int* __restrict__ dst, int* __restrict__ cnt){
  int i=blockIdx.x*blockDim.x+threadIdx.x;
  if(i>=N_EDGESC) return;
  atomicAdd(&cnt[dst[i]],1);
}

__global__ void k_scan(const int* __restrict__ cnt, int* __restrict__ rptr, int* __restrict__ pos){
  __shared__ int ps[1024];
  int t=threadIdx.x;
  const int CH=20;
  int beg=t*CH, end=min(beg+CH, N_NODESC);
  int s=0;
  for(int i=beg;i<end;i++) s+=cnt[i];
  ps[t]=s; __syncthreads();
  for(int off=1;off<1024;off<<=1){
    int v=(t>=off)? ps[t-off]:0;
    __syncthreads();
    ps[t]+=v;
    __syncthreads();
  }
  int base=ps[t]-s;
  for(int i=beg;i<end;i++){ rptr[i]=base; pos[i]=base; base+=cnt[i]; }
}

__global__ void k_scatter(const int* __restrict__ dst, int* __restrict__ pos, int* __restrict__ eidx){
  int i=blockIdx.x*blockDim.x+threadIdx.x;
  if(i>=N_EDGESC) return;
  int j=atomicAdd(&pos[dst[i]],1);
  eidx[j]=i;
}

// scatter-mean of edge_attr per dst node via CSR (no atomics); one wave per node
__global__ __launch_bounds__(256) void k_loop_attr(const float* __restrict__ eattr,
    const int* __restrict__ rptr, const int* __restrict__ cnt, const int* __restrict__ eidx,
    float* __restrict__ lattr){
  int tid=threadIdx.x, lane=tid&63;
  int n=blockIdx.x*4+(tid>>6);
  if(n>=N_NODESC) return;
  int beg=rptr[n], deg=cnt[n];
  float s[10]={0,0,0,0,0,0,0,0,0,0};
  for(int off=lane; off<deg; off+=64){
    int e=eidx[beg+off];
    const float* ep=&eattr[(size_t)e*10];
    #pragma unroll
    for(int k=0;k<10;k++) s[k]+=ep[k];
  }
  float inv=1.f/fmaxf((float)deg,1.f);
  #pragma unroll
  for(int k=0;k<10;k++){
    float tot=wred_sum(s[k]);
    if(lane==0) lattr[(size_t)n*10+k]=tot*inv;
  }
}

// ---------------- conversions ----------------

__global__ void k_conv_x(const float* __restrict__ x, u16* __restrict__ hi, u16* __restrict__ lo){
  int idx=blockIdx.x*blockDim.x+threadIdx.x;
  if(idx>=N_NODESC*64) return;
  int n=idx>>6, kk=idx&63;
  float v = kk<43 ? x[n*43+kk] : 0.f;
  u16 h=f2bf(v);
  hi[idx]=h; lo[idx]=f2bf(v-bf2f(h));
}

__global__ void k_conv_w(const float* __restrict__ W, u16* __restrict__ hi, u16* __restrict__ lo,
                         int KL, int KP){
  int idx=blockIdx.x*blockDim.x+threadIdx.x;
  if(idx>=HC*KP) return;
  int kk=idx/HC;
  int n=idx-kk*HC;
  float v = kk<KL ? W[(size_t)kk*HC+n] : 0.f;
  u16 h=f2bf(v);
  hi[(size_t)n*KP+kk]=h;
  lo[(size_t)n*KP+kk]=f2bf(v-bf2f(h));
}

// ---------------- per-layer kernels ----------------

__global__ void k_ve(const float* __restrict__ We, const float* __restrict__ aedge,
                     float* __restrict__ ve){
  int t=threadIdx.x;
  if(t>=50) return;
  int k=t/5, h=t%5;
  float s=0.f;
  for(int c=0;c<128;c++) s += We[k*HC + h*128 + c]*aedge[h*128+c];
  ve[k*5+h]=s;
}

// ael[n][h] = lattr[n,:] . ve[:,h]
__global__ void k_ael(const float* __restrict__ lattr, const float* __restrict__ ve,
                      float* __restrict__ ael){
  int idx=blockIdx.x*blockDim.x+threadIdx.x;
  if(idx>=N_NODESC*5) return;
  int n=idx/5, h=idx-5*n;
  float s=0.f;
  #pragma unroll
  for(int k=0;k<10;k++) s+=lattr[(size_t)n*10+k]*ve[k*5+h];
  ael[idx]=s;
}

// Fused GEMM + nodeatt: writes permuted bf16 hb + per-head al/ar.
// NT=3: C=Ahi@Bhi+Alo@Bhi+Ahi@Blo (layer 0, tiny K). NT=1: C=A@Bhi (pure bf16).
// BK=32, double-buffered LDS. NT=1: 32 KiB -> 5 blocks/CU.
// 128x128 tile, 4 waves each 64x64, XCD-bijective swizzle.
template<int NT>
__global__ __launch_bounds__(256,(NT==1)?5:3) void k_gemm_fused(
    const u16* __restrict__ Ahi, const u16* __restrict__ Alo,
    const u16* __restrict__ Bhi, const u16* __restrict__ Blo,
    const float* __restrict__ asrc, const float* __restrict__ adst,
    u16* __restrict__ hb, float* __restrict__ al, float* __restrict__ ar,
    int M, int KP, int nblk){
  constexpr int TERMS=(NT==3)?4:2;
  constexpr int BOFF =(NT==3)?8192:4096;     // B-hi offset within buffer
  __shared__ u16 lds[2*TERMS*4096];
  int tid=threadIdx.x;
  int lane=tid&63;
  int w=tid>>6;
  int l15=lane&15, lg=lane>>4;
  // XCD-bijective swizzle: contiguous wg chunks per XCD
  int orig=blockIdx.x;
  int q=nblk>>3, r=nblk&7;
  int xcd=orig&7, off=orig>>3;
  int wg=(xcd<r? xcd*(q+1) : r*(q+1)+(xcd-r)*q)+off;
  int by=wg/5, bx=wg-5*by;
  int row0=by*128, col0=bx*128;
  int wr=w>>1, wc=w&1;

  f32x4 zero = {0.f,0.f,0.f,0.f};
  f32x4 acc[4][4];
  #pragma unroll
  for(int i=0;i<4;i++)
    #pragma unroll
    for(int j=0;j<4;j++) acc[i][j]=zero;

  auto stage=[&](int b, int k0){
    u16* base = lds + b*TERMS*4096;
    #pragma unroll
    for(int c=0;c<2;c++){
      int sb=w+4*c;                          // 8 sub-blocks of 16 rows x 32 k
      int col=k0+lg*8;
      size_t aoff=(size_t)(row0+sb*16+l15)*KP + col;
      size_t boff=(size_t)(col0+sb*16+l15)*KP + col;
      gload16(Ahi+aoff, base + sb*512);
      if constexpr(NT==3) gload16(Alo+aoff, base+4096 + sb*512);
      gload16(Bhi+boff, base+BOFF + sb*512);
      if constexpr(NT==3) gload16(Blo+boff, base+BOFF+4096 + sb*512);
    }
  };

  int nt=KP/32;
  stage(0,0);
  __syncthreads();
  int cur=0;
  for(int t=0;t<nt;t++){
    if(t+1<nt) stage(cur^1,(t+1)*32);
    u16* cb = lds + cur*TERMS*4096;
    bf16x8 ah[4], bh[4];
    #pragma unroll
    for(int i=0;i<4;i++){
      ah[i]=*(const bf16x8*)&cb[(wr*4+i)*512 + lane*8];
      bh[i]=*(const bf16x8*)&cb[BOFF+(wc*4+i)*512 + lane*8];
    }
    if constexpr(NT==3){
      bf16x8 alv[4], bl[4];
      #pragma unroll
      for(int i=0;i<4;i++){
        alv[i]=*(const bf16x8*)&cb[4096+(wr*4+i)*512+lane*8];
        bl[i] =*(const bf16x8*)&cb[BOFF+4096+(wc*4+i)*512+lane*8];
      }
      #pragma unroll
      for(int i=0;i<4;i++)
        #pragma unroll
        for(int j=0;j<4;j++){
          acc[i][j]=__builtin_amdgcn_mfma_f32_16x16x32_bf16(ah[i], bh[j],acc[i][j],0,0,0);
          acc[i][j]=__builtin_amdgcn_mfma_f32_16x16x32_bf16(alv[i],bh[j],acc[i][j],0,0,0);
          acc[i][j]=__builtin_amdgcn_mfma_f32_16x16x32_bf16(ah[i], bl[j],acc[i][j],0,0,0);
        }
    }else{
      #pragma unroll
      for(int i=0;i<4;i++)
        #pragma unroll
        for(int j=0;j<4;j++)
          acc[i][j]=__builtin_amdgcn_mfma_f32_16x16x32_bf16(ah[i],bh[j],acc[i][j],0,0,0);
    }
    __syncthreads();
    cur^=1;
  }

  // ---- epilogue: hb (permuted bf16) + al/ar for head bx ----
  float asv[4], adv[4];
  #pragma unroll
  for(int j=0;j<4;j++){
    int c=col0+wc*64+j*16+l15;
    asv[j]=asrc[c]; adv[j]=adst[c];
  }
  // hb[n*640 + (c&63)*10 + (c>>6)] ; c&63 = j*16+l15 ; c>>6 = bx*2+wc
  #pragma unroll
  for(int i=0;i<4;i++){
    #pragma unroll
    for(int j=0;j<4;j++){
      #pragma unroll
      for(int rr=0;rr<4;rr++){
        int row=row0+wr*64+i*16+lg*4+rr;
        if(row<M) hb[(size_t)row*HC + (j*16+l15)*10 + bx*2+wc]=f2bf(acc[i][j][rr]);
      }
    }
  }
  // per-row partial dot over this wave's 64 cols, reduce across l15
  float* redAl=(float*)lds;       // 512 floats scratch
  float* redAr=redAl+256;
  #pragma unroll
  for(int i=0;i<4;i++){
    #pragma unroll
    for(int rr=0;rr<4;rr++){
      float sa=0.f, sd=0.f;
      #pragma unroll
      for(int j=0;j<4;j++){ sa+=acc[i][j][rr]*asv[j]; sd+=acc[i][j][rr]*adv[j]; }
      #pragma unroll
      for(int o=1;o<16;o<<=1){ sa+=__shfl_xor(sa,o,64); sd+=__shfl_xor(sd,o,64); }
      if(l15==0){
        int lr=wr*64+i*16+lg*4+rr;
        redAl[lr*2+wc]=sa; redAr[lr*2+wc]=sd;
      }
    }
  }
  __syncthreads();
  if(tid<128){
    int row=row0+tid;
    if(row<M){
      al[(size_t)row*5+bx]=redAl[tid*2]+redAl[tid*2+1];
      ar[(size_t)row*5+bx]=redAr[tid*2]+redAr[tid*2+1];
    }
  }
}

__global__ void k_ae(const float* __restrict__ eattr, const float* __restrict__ ve,
                     float* __restrict__ ae){
  __shared__ float ves[50];
  if(threadIdx.x<50) ves[threadIdx.x]=ve[threadIdx.x];
  __syncthreads();
  int i=blockIdx.x*blockDim.x+threadIdx.x;
  if(i>=N_EDGESC) return;
  float ev[10];
  #pragma unroll
  for(int k=0;k<10;k++) ev[k]=eattr[i*10+k];
  #pragma unroll
  for(int hh=0;hh<5;hh++){
    float s=0.f;
    #pragma unroll
    for(int k=0;k<10;k++) s+=ev[k]*ves[k*5+hh];
    ae[(size_t)i*5+hh]=s;
  }
}

// fused segment-softmax + aggregation; one wave per node. Gathers bf16 hb rows
// with a 4-deep unrolled inner loop (4 rows in flight).
// WBF: write bf16 (next layer GEMM A input). else: write f32 out.
template<bool RELU, bool WBF>
__global__ __launch_bounds__(256) void k_agg(const u16* __restrict__ hb, const int* __restrict__ src,
    const int* __restrict__ rptr, const int* __restrict__ cnt, const int* __restrict__ eidx,
    const float* __restrict__ al, const float* __restrict__ ar, const float* __restrict__ ael,
    const float* __restrict__ ae, const float* __restrict__ bias,
    float* __restrict__ out, u16* __restrict__ ohi){
  int tid=threadIdx.x, lane=tid&63;
  int n=blockIdx.x*4+(tid>>6);
  if(n>=N_NODESC) return;
  float arn[5], m[5], den[5], acc[10];
  #pragma unroll
  for(int hh=0;hh<5;hh++) arn[hh]=ar[n*5+hh];
  #pragma unroll
  for(int hh=0;hh<5;hh++){
    m[hh]=lrelu(al[n*5+hh]+arn[hh]+ael[n*5+hh]);
    den[hh]=1.f;
  }
  {
    const u32* sp=(const u32*)(hb+(size_t)n*HC+lane*10);
    #pragma unroll
    for(int j2=0;j2<5;j2++){
      u32 wv=sp[j2];
      acc[2*j2]  =bflo(wv);
      acc[2*j2+1]=bfhi(wv);
    }
  }
  int beg=rptr[n], deg=cnt[n];
  for(int off0=0; off0<deg; off0+=64){
    int c=min(64,deg-off0);
    bool valid = lane<c;
    int s=0; float p[5];
    #pragma unroll
    for(int hh=0;hh<5;hh++) p[hh]=-1e30f;
    if(valid){
      int e=eidx[beg+off0+lane];
      s=src[e];
      #pragma unroll
      for(int hh=0;hh<5;hh++) p[hh]=lrelu(al[s*5+hh]+arn[hh]+ae[(size_t)e*5+hh]);
    }
    float sc[5];
    #pragma unroll
    for(int hh=0;hh<5;hh++){
      float cm=wred_max(p[hh]);
      float nm=fmaxf(m[hh],cm);
      sc[hh]=__expf(m[hh]-nm);
      den[hh]*=sc[hh];
      float pv = valid? __expf(p[hh]-nm) : 0.f;
      p[hh]=pv;
      den[hh]+=wred_sum(pv);
      m[hh]=nm;
    }
    #pragma unroll
    for(int k=0;k<10;k++) acc[k]*=sc[k>>1];
    int j=0;
    for(; j+3<c; j+=4){
      int sjv[4];
      float pjv[4][5];
      u32 wv[4][5];
      #pragma unroll
      for(int u=0;u<4;u++) sjv[u]=__shfl(s,j+u,64);
      #pragma unroll
      for(int u=0;u<4;u++)
        #pragma unroll
        for(int hh=0;hh<5;hh++) pjv[u][hh]=__shfl(p[hh],j+u,64);
      #pragma unroll
      for(int u=0;u<4;u++){
        const u32* hr=(const u32*)(hb+(size_t)sjv[u]*HC+lane*10);
        #pragma unroll
        for(int j2=0;j2<5;j2++) wv[u][j2]=hr[j2];
      }
      #pragma unroll
      for(int u=0;u<4;u++)
        #pragma unroll
        for(int j2=0;j2<5;j2++){
          acc[2*j2]  +=pjv[u][j2]*bflo(wv[u][j2]);
          acc[2*j2+1]+=pjv[u][j2]*bfhi(wv[u][j2]);
        }
    }
    for(; j<c; j++){
      int sj=__shfl(s,j,64);
      float pj[5];
      #pragma unroll
      for(int hh=0;hh<5;hh++) pj[hh]=__shfl(p[hh],j,64);
      const u32* hr=(const u32*)(hb+(size_t)sj*HC+lane*10);
      #pragma unroll
      for(int j2=0;j2<5;j2++){
        u32 wv=hr[j2];
        acc[2*j2]  +=pj[j2]*bflo(wv);
        acc[2*j2+1]+=pj[j2]*bfhi(wv);
      }
    }
  }
  #pragma unroll
  for(int k=0;k<10;k++){
    int ccol=lane+64*k;
    float v=acc[k]/(den[k>>1]+1e-16f)+bias[ccol];
    if(RELU) v=fmaxf(v,0.f);
    if(WBF){
      ohi[(size_t)n*HC+ccol]=f2bf(v);
    }else{
      out[(size_t)n*HC+ccol]=v;
    }
  }
}

// ---------------- pooling + head ----------------

__global__ __launch_bounds__(256) void k_pool(const float* __restrict__ h, const float* __restrict__ wlin,
    const int* __restrict__ batch, float* __restrict__ ysum, float* __restrict__ cntg){
  int tid=threadIdx.x, lane=tid&63;
  int n=blockIdx.x*4+(tid>>6);
  if(n>=N_NODESC) return;
  float s=0.f;
  #pragma unroll
  for(int k=0;k<10;k++){ int c=lane+64*k; s+=h[(size_t)n*HC+c]*wlin[c]; }
  s=wred_sum(s);
  if(lane==0){
    int g=batch[n];
    atomicAdd(&ysum[g],s);
    atomicAdd(&cntg[g],1.f);
  }
}

__global__ void k_final(const float* __restrict__ ysum, const float* __restrict__ cntg,
                        const float* __restrict__ blin, float* __restrict__ out){
  int g=blockIdx.x*blockDim.x+threadIdx.x;
  if(g>=NGRAPH) return;
  out[g]=ysum[g]/fmaxf(cntg[g],1.f)+blin[0];
}

// ---------------- launch ----------------

extern "C" void kernel_launch(void* const* d_in, const int* in_sizes, int n_in,
                              void* d_out, int out_size, void* d_ws, size_t ws_size,
                              hipStream_t stream){
  const float* x     = (const float*)d_in[0];
  const float* eattr = (const float*)d_in[1];
  const float* W[3]    ={(const float*)d_in[2],(const float*)d_in[8],(const float*)d_in[14]};
  const float* We[3]   ={(const float*)d_in[3],(const float*)d_in[9],(const float*)d_in[15]};
  const float* asrc[3] ={(const float*)d_in[4],(const float*)d_in[10],(const float*)d_in[16]};
  const float* adst[3] ={(const float*)d_in[5],(const float*)d_in[11],(const float*)d_in[17]};
  const float* aedge[3]={(const float*)d_in[6],(const float*)d_in[12],(const float*)d_in[18]};
  const float* bias[3] ={(const float*)d_in[7],(const float*)d_in[13],(const float*)d_in[19]};
  const float* Wlin  = (const float*)d_in[20];
  const float* blin  = (const float*)d_in[21];
  const int* eind    = (const int*)d_in[22];
  const int* srcp    = eind;
  const int* dstp    = eind + N_EDGESC;
  const int* batch   = (const int*)d_in[23];
  float* out = (float*)d_out;

  char* ws=(char*)d_ws;
  size_t o=0;
  auto alloc=[&](size_t bytes)->void*{ void* p=ws+o; o=(o+bytes+255)&~(size_t)255; return p; };
  u16* hb   =(u16*)alloc((size_t)N_NODESC*HC*2);           // permuted bf16 h
  float* aggf =(float*)alloc((size_t)N_NODESC*HC*4);       // final layer f32 out
  u16* Ahi =(u16*)alloc((size_t)N_NODESC*HC*2);            // agg bf16 out (next GEMM A)
  u16* Axhi=(u16*)alloc((size_t)N_NODESC*64*2);            // converted x (KP=64)
  u16* Axlo=(u16*)alloc((size_t)N_NODESC*64*2);
  u16* Bthi=(u16*)alloc((size_t)HC*HC*2);                  // transposed weights
  u16* Btlo=(u16*)alloc((size_t)HC*HC*2);
  float* al   =(float*)alloc((size_t)N_NODESC*5*4);
  float* ar   =(float*)alloc((size_t)N_NODESC*5*4);
  float* ael  =(float*)alloc((size_t)N_NODESC*5*4);
  float* ae   =(float*)alloc((size_t)N_EDGESC*5*4);
  float* lattr=(float*)alloc((size_t)N_NODESC*10*4);
  float* ve   =(float*)alloc(64*4);
  float* ysum =(float*)alloc(512*4);
  float* cntg =(float*)alloc(512*4);
  int* cntI   =(int*)alloc((size_t)N_NODESC*4);
  int* rptr   =(int*)alloc((size_t)N_NODESC*4);
  int* pos    =(int*)alloc((size_t)N_NODESC*4);
  int* eidx   =(int*)alloc((size_t)N_EDGESC*4);

  hipMemsetAsync(cntI,0,(size_t)N_NODESC*4,stream);
  hipMemsetAsync(ysum,0,512*4,stream);
  hipMemsetAsync(cntg,0,512*4,stream);

  k_count<<<(N_EDGESC+255)/256,256,0,stream>>>(dstp,cntI);
  k_scan<<<1,1024,0,stream>>>(cntI,rptr,pos);
  k_scatter<<<(N_EDGESC+255)/256,256,0,stream>>>(dstp,pos,eidx);
  k_loop_attr<<<(N_NODESC+3)/4,256,0,stream>>>(eattr,rptr,cntI,eidx,lattr);
  k_conv_x<<<(N_NODESC*64+255)/256,256,0,stream>>>(x,Axhi,Axlo);

  const int NBLK=5*((N_NODESC+127)/128);
  for(int L=0;L<3;L++){
    int KL = (L==0)? 43 : HC;
    int KP = (L==0)? 64 : HC;
    k_ve<<<1,64,0,stream>>>(We[L],aedge[L],ve);
    k_conv_w<<<(HC*KP+255)/256,256,0,stream>>>(W[L],Bthi,Btlo,KL,KP);
    if(L==0)
      k_gemm_fused<3><<<NBLK,256,0,stream>>>(Axhi,Axlo,Bthi,Btlo,asrc[L],adst[L],hb,al,ar,N_NODESC,KP,NBLK);
    else
      k_gemm_fused<1><<<NBLK,256,0,stream>>>(Ahi,(const u16*)nullptr,Bthi,(const u16*)nullptr,asrc[L],adst[L],hb,al,ar,N_NODESC,KP,NBLK);
    k_ael<<<(N_NODESC*5+255)/256,256,0,stream>>>(lattr,ve,ael);
    k_ae<<<(N_EDGESC+255)/256,256,0,stream>>>(eattr,ve,ae);
    if(L<2)
      k_agg<true ,true ><<<(N_NODESC+3)/4,256,0,stream>>>(hb,srcp,rptr,cntI,eidx,al,ar,ael,ae,bias[L],aggf,Ahi);
    else
      k_agg<false,false><<<(N_NODESC+3)/4,256,0,stream>>>(hb,srcp,rptr,cntI,eidx,al,ar,ael,ae,bias[L],aggf,Ahi);
  }
  k_pool<<<(N_NODESC+3)/4,256,0,stream>>>(aggf,Wlin,batch,ysum,cntg);
  k_final<<<2,256,0,stream>>>(ysum,cntg,blin,out);
}

// Round 11
// 570.781 us; speedup vs baseline: 1.0663x; 1.0220x over previous
//
#include <hip/hip_runtime.h>

#define N_NODESC 20000
#define N_EDGESC 320000
#define HC 640
#define NGRAPH 500

typedef unsigned short u16;
typedef unsigned int u32;
typedef __attribute__((ext_vector_type(8))) short bf16x8;
typedef __attribute__((ext_vector_type(4))) float f32x4;

__device__ __forceinline__ float wred_sum(float v){
  #pragma unroll
  for(int o=32;o;o>>=1) v += __shfl_xor(v,o,64);
  return v;
}
__device__ __forceinline__ float wred_max(float v){
  #pragma unroll
  for(int o=32;o;o>>=1) v = fmaxf(v,__shfl_xor(v,o,64));
  return v;
}
__device__ __forceinline__ float lrelu(float x){ return x>0.f? x:0.2f*x; }

__device__ __forceinline__ u16 f2bf(float f){
  u32 u=__float_as_uint(f);
  u32 r=u+0x7FFFu+((u>>16)&1u);
  return (u16)(r>>16);
}
__device__ __forceinline__ float bf2f(u16 s){ return __uint_as_float(((u32)s)<<16); }
__device__ __forceinline__ float bflo(u32 w){ return __uint_as_float(w<<16); }
__device__ __forceinline__ float bfhi(u32 w){ return __uint_as_float(w&0xFFFF0000u); }

__device__ __forceinline__ void gload16(const void* g, void* l){
  __builtin_amdgcn_global_load_lds((const __attribute__((address_space(1))) void*)g,
                                   (__attribute__((address_space(3))) void*)l, 16, 0, 0);
}

// ---------------- graph preprocessing (layer-invariant) ----------------

__global__ void k_count(const int* __restrict__ dst, int* __restrict__ cnt){
  int i=blockIdx.x*blockDim.x+threadIdx.x;
  if(i>=N_EDGESC) return;
  atomicAdd(&cnt[dst[i]],1);
}

__global__ void k_scan(const int* __restrict__ cnt, int* __restrict__ rptr, int* __restrict__ pos){
  __shared__ int ps[1024];
  int t=threadIdx.x;
  const int CH=20;
  int beg=t*CH, end=min(beg+CH, N_NODESC);
  int s=0;
  for(int i=beg;i<end;i++) s+=cnt[i];
  ps[t]=s; __syncthreads();
  for(int off=1;off<1024;off<<=1){
    int v=(t>=off)? ps[t-off]:0;
    __syncthreads();
    ps[t]+=v;
    __syncthreads();
  }
  int base=ps[t]-s;
  for(int i=beg;i<end;i++){ rptr[i]=base; pos[i]=base; base+=cnt[i]; }
}

__global__ void k_scatter(const int* __restrict__ dst, int* __restrict__ pos, int* __restrict__ eidx){
  int i=blockIdx.x*blockDim.x+threadIdx.x;
  if(i>=N_EDGESC) return;
  int j=atomicAdd(&pos[dst[i]],1);
  eidx[j]=i;
}

// resolve CSR permutation ONCE: srcE[j]=src[eidx[j]], eattrC[j]=eattr[eidx[j]]
__global__ void k_csr_edges(const int* __restrict__ eidx, const int* __restrict__ src,
                            const float* __restrict__ eattr,
                            int* __restrict__ srcE, float* __restrict__ eattrC){
  int j=blockIdx.x*blockDim.x+threadIdx.x;
  if(j>=N_EDGESC) return;
  int e=eidx[j];
  srcE[j]=src[e];
  const float* ep=&eattr[(size_t)e*10];
  float* op=&eattrC[(size_t)j*10];
  #pragma unroll
  for(int k=0;k<10;k++) op[k]=ep[k];
}

// scatter-mean of edge_attr per dst node via CSR (linear reads); one wave per node
__global__ __launch_bounds__(256) void k_loop_attr(const float* __restrict__ eattrC,
    const int* __restrict__ rptr, const int* __restrict__ cnt,
    float* __restrict__ lattr){
  int tid=threadIdx.x, lane=tid&63;
  int n=blockIdx.x*4+(tid>>6);
  if(n>=N_NODESC) return;
  int beg=rptr[n], deg=cnt[n];
  float s[10]={0,0,0,0,0,0,0,0,0,0};
  for(int off=lane; off<deg; off+=64){
    const float* ep=&eattrC[(size_t)(beg+off)*10];
    #pragma unroll
    for(int k=0;k<10;k++) s[k]+=ep[k];
  }
  float inv=1.f/fmaxf((float)deg,1.f);
  #pragma unroll
  for(int k=0;k<10;k++){
    float tot=wred_sum(s[k]);
    if(lane==0) lattr[(size_t)n*10+k]=tot*inv;
  }
}

// ---------------- conversions ----------------

__global__ void k_conv_x(const float* __restrict__ x, u16* __restrict__ hi, u16* __restrict__ lo){
  int idx=blockIdx.x*blockDim.x+threadIdx.x;
  if(idx>=N_NODESC*64) return;
  int n=idx>>6, kk=idx&63;
  float v = kk<43 ? x[n*43+kk] : 0.f;
  u16 h=f2bf(v);
  hi[idx]=h; lo[idx]=f2bf(v-bf2f(h));
}

__global__ void k_conv_w(const float* __restrict__ W, u16* __restrict__ hi, u16* __restrict__ lo,
                         int KL, int KP){
  int idx=blockIdx.x*blockDim.x+threadIdx.x;
  if(idx>=HC*KP) return;
  int kk=idx/HC;
  int n=idx-kk*HC;
  float v = kk<KL ? W[(size_t)kk*HC+n] : 0.f;
  u16 h=f2bf(v);
  hi[(size_t)n*KP+kk]=h;
  lo[(size_t)n*KP+kk]=f2bf(v-bf2f(h));
}

// ---------------- per-layer kernels ----------------

__global__ void k_ve(const float* __restrict__ We, const float* __restrict__ aedge,
                     float* __restrict__ ve){
  int t=threadIdx.x;
  if(t>=50) return;
  int k=t/5, h=t%5;
  float s=0.f;
  for(int c=0;c<128;c++) s += We[k*HC + h*128 + c]*aedge[h*128+c];
  ve[k*5+h]=s;
}

// fused: aeC[j][h] (CSR-order edge logits) for idx<E; ael[n][h] for idx>=E
__global__ __launch_bounds__(256) void k_edge_terms(const float* __restrict__ eattrC,
    const float* __restrict__ lattr, const float* __restrict__ ve,
    float* __restrict__ aeC, float* __restrict__ ael){
  __shared__ float ves[50];
  if(threadIdx.x<50) ves[threadIdx.x]=ve[threadIdx.x];
  __syncthreads();
  int idx=blockIdx.x*blockDim.x+threadIdx.x;
  if(idx<N_EDGESC){
    float ev[10];
    const float* ep=&eattrC[(size_t)idx*10];
    #pragma unroll
    for(int k=0;k<10;k++) ev[k]=ep[k];
    #pragma unroll
    for(int hh=0;hh<5;hh++){
      float s=0.f;
      #pragma unroll
      for(int k=0;k<10;k++) s+=ev[k]*ves[k*5+hh];
      aeC[(size_t)idx*5+hh]=s;
    }
  }else{
    int t=idx-N_EDGESC;
    if(t<N_NODESC*5){
      int n=t/5, h=t-5*n;
      float s=0.f;
      #pragma unroll
      for(int k=0;k<10;k++) s+=lattr[(size_t)n*10+k]*ves[k*5+h];
      ael[t]=s;
    }
  }
}

// Fused GEMM + nodeatt: writes permuted bf16 hb + per-head al/ar.
// NT=3: C=Ahi@Bhi+Alo@Bhi+Ahi@Blo (layer 0, tiny K). NT=1: C=A@Bhi (pure bf16).
// BK=32, double-buffered LDS. NT=1: 32 KiB -> 5 blocks/CU.
// 128x128 tile, 4 waves each 64x64, XCD-bijective swizzle.
template<int NT>
__global__ __launch_bounds__(256,(NT==1)?5:3) void k_gemm_fused(
    const u16* __restrict__ Ahi, const u16* __restrict__ Alo,
    const u16* __restrict__ Bhi, const u16* __restrict__ Blo,
    const float* __restrict__ asrc, const float* __restrict__ adst,
    u16* __restrict__ hb, float* __restrict__ al, float* __restrict__ ar,
    int M, int KP, int nblk){
  constexpr int TERMS=(NT==3)?4:2;
  constexpr int BOFF =(NT==3)?8192:4096;     // B-hi offset within buffer
  __shared__ u16 lds[2*TERMS*4096];
  int tid=threadIdx.x;
  int lane=tid&63;
  int w=tid>>6;
  int l15=lane&15, lg=lane>>4;
  // XCD-bijective swizzle: contiguous wg chunks per XCD
  int orig=blockIdx.x;
  int q=nblk>>3, r=nblk&7;
  int xcd=orig&7, off=orig>>3;
  int wg=(xcd<r? xcd*(q+1) : r*(q+1)+(xcd-r)*q)+off;
  int by=wg/5, bx=wg-5*by;
  int row0=by*128, col0=bx*128;
  int wr=w>>1, wc=w&1;

  f32x4 zero = {0.f,0.f,0.f,0.f};
  f32x4 acc[4][4];
  #pragma unroll
  for(int i=0;i<4;i++)
    #pragma unroll
    for(int j=0;j<4;j++) acc[i][j]=zero;

  auto stage=[&](int b, int k0){
    u16* base = lds + b*TERMS*4096;
    #pragma unroll
    for(int c=0;c<2;c++){
      int sb=w+4*c;                          // 8 sub-blocks of 16 rows x 32 k
      int col=k0+lg*8;
      size_t aoff=(size_t)(row0+sb*16+l15)*KP + col;
      size_t boff=(size_t)(col0+sb*16+l15)*KP + col;
      gload16(Ahi+aoff, base + sb*512);
      if constexpr(NT==3) gload16(Alo+aoff, base+4096 + sb*512);
      gload16(Bhi+boff, base+BOFF + sb*512);
      if constexpr(NT==3) gload16(Blo+boff, base+BOFF+4096 + sb*512);
    }
  };

  int nt=KP/32;
  stage(0,0);
  __syncthreads();
  int cur=0;
  for(int t=0;t<nt;t++){
    if(t+1<nt) stage(cur^1,(t+1)*32);
    u16* cb = lds + cur*TERMS*4096;
    bf16x8 ah[4], bh[4];
    #pragma unroll
    for(int i=0;i<4;i++){
      ah[i]=*(const bf16x8*)&cb[(wr*4+i)*512 + lane*8];
      bh[i]=*(const bf16x8*)&cb[BOFF+(wc*4+i)*512 + lane*8];
    }
    if constexpr(NT==3){
      bf16x8 alv[4], bl[4];
      #pragma unroll
      for(int i=0;i<4;i++){
        alv[i]=*(const bf16x8*)&cb[4096+(wr*4+i)*512+lane*8];
        bl[i] =*(const bf16x8*)&cb[BOFF+4096+(wc*4+i)*512+lane*8];
      }
      #pragma unroll
      for(int i=0;i<4;i++)
        #pragma unroll
        for(int j=0;j<4;j++){
          acc[i][j]=__builtin_amdgcn_mfma_f32_16x16x32_bf16(ah[i], bh[j],acc[i][j],0,0,0);
          acc[i][j]=__builtin_amdgcn_mfma_f32_16x16x32_bf16(alv[i],bh[j],acc[i][j],0,0,0);
          acc[i][j]=__builtin_amdgcn_mfma_f32_16x16x32_bf16(ah[i], bl[j],acc[i][j],0,0,0);
        }
    }else{
      #pragma unroll
      for(int i=0;i<4;i++)
        #pragma unroll
        for(int j=0;j<4;j++)
          acc[i][j]=__builtin_amdgcn_mfma_f32_16x16x32_bf16(ah[i],bh[j],acc[i][j],0,0,0);
    }
    __syncthreads();
    cur^=1;
  }

  // ---- epilogue: hb (permuted bf16) + al/ar for head bx ----
  float asv[4], adv[4];
  #pragma unroll
  for(int j=0;j<4;j++){
    int c=col0+wc*64+j*16+l15;
    asv[j]=asrc[c]; adv[j]=adst[c];
  }
  // hb[n*640 + (c&63)*10 + (c>>6)] ; c&63 = j*16+l15 ; c>>6 = bx*2+wc
  #pragma unroll
  for(int i=0;i<4;i++){
    #pragma unroll
    for(int j=0;j<4;j++){
      #pragma unroll
      for(int rr=0;rr<4;rr++){
        int row=row0+wr*64+i*16+lg*4+rr;
        if(row<M) hb[(size_t)row*HC + (j*16+l15)*10 + bx*2+wc]=f2bf(acc[i][j][rr]);
      }
    }
  }
  // per-row partial dot over this wave's 64 cols, reduce across l15
  float* redAl=(float*)lds;       // 512 floats scratch
  float* redAr=redAl+256;
  #pragma unroll
  for(int i=0;i<4;i++){
    #pragma unroll
    for(int rr=0;rr<4;rr++){
      float sa=0.f, sd=0.f;
      #pragma unroll
      for(int j=0;j<4;j++){ sa+=acc[i][j][rr]*asv[j]; sd+=acc[i][j][rr]*adv[j]; }
      #pragma unroll
      for(int o=1;o<16;o<<=1){ sa+=__shfl_xor(sa,o,64); sd+=__shfl_xor(sd,o,64); }
      if(l15==0){
        int lr=wr*64+i*16+lg*4+rr;
        redAl[lr*2+wc]=sa; redAr[lr*2+wc]=sd;
      }
    }
  }
  __syncthreads();
  if(tid<128){
    int row=row0+tid;
    if(row<M){
      al[(size_t)row*5+bx]=redAl[tid*2]+redAl[tid*2+1];
      ar[(size_t)row*5+bx]=redAr[tid*2]+redAr[tid*2+1];
    }
  }
}

// fused segment-softmax + aggregation; one wave per node. Linear CSR edge data
// (srcE, aeC), L2-resident al gather, 8-deep unrolled hb row gather.
// WBF: write bf16 (next layer GEMM A input). else: write f32 out.
template<bool RELU, bool WBF>
__global__ __launch_bounds__(256) void k_agg(const u16* __restrict__ hb, const int* __restrict__ srcE,
    const int* __restrict__ rptr, const int* __restrict__ cnt,
    const float* __restrict__ al, const float* __restrict__ ar, const float* __restrict__ ael,
    const float* __restrict__ aeC, const float* __restrict__ bias,
    float* __restrict__ out, u16* __restrict__ ohi){
  int tid=threadIdx.x, lane=tid&63;
  int n=blockIdx.x*4+(tid>>6);
  if(n>=N_NODESC) return;
  float arn[5], m[5], den[5], acc[10];
  #pragma unroll
  for(int hh=0;hh<5;hh++) arn[hh]=ar[n*5+hh];
  #pragma unroll
  for(int hh=0;hh<5;hh++){
    m[hh]=lrelu(al[n*5+hh]+arn[hh]+ael[n*5+hh]);
    den[hh]=1.f;
  }
  {
    const u32* sp=(const u32*)(hb+(size_t)n*HC+lane*10);
    #pragma unroll
    for(int j2=0;j2<5;j2++){
      u32 wv=sp[j2];
      acc[2*j2]  =bflo(wv);
      acc[2*j2+1]=bfhi(wv);
    }
  }
  int beg=rptr[n], deg=cnt[n];
  for(int off0=0; off0<deg; off0+=64){
    int c=min(64,deg-off0);
    bool valid = lane<c;
    int s=0; float p[5];
    #pragma unroll
    for(int hh=0;hh<5;hh++) p[hh]=-1e30f;
    if(valid){
      int j=beg+off0+lane;
      s=srcE[j];                                   // linear
      const float* av=&aeC[(size_t)j*5];           // linear
      #pragma unroll
      for(int hh=0;hh<5;hh++) p[hh]=lrelu(al[s*5+hh]+arn[hh]+av[hh]);
    }
    float sc[5];
    #pragma unroll
    for(int hh=0;hh<5;hh++){
      float cm=wred_max(p[hh]);
      float nm=fmaxf(m[hh],cm);
      sc[hh]=__expf(m[hh]-nm);
      den[hh]*=sc[hh];
      float pv = valid? __expf(p[hh]-nm) : 0.f;
      p[hh]=pv;
      den[hh]+=wred_sum(pv);
      m[hh]=nm;
    }
    #pragma unroll
    for(int k=0;k<10;k++) acc[k]*=sc[k>>1];
    int j=0;
    for(; j+7<c; j+=8){
      int sjv[8];
      #pragma unroll
      for(int u=0;u<8;u++) sjv[u]=__shfl(s,j+u,64);
      u32 wv[8][5];
      #pragma unroll
      for(int u=0;u<8;u++){
        const u32* hr=(const u32*)(hb+(size_t)sjv[u]*HC+lane*10);
        #pragma unroll
        for(int j2=0;j2<5;j2++) wv[u][j2]=hr[j2];
      }
      #pragma unroll
      for(int u=0;u<8;u++){
        float pj[5];
        #pragma unroll
        for(int hh=0;hh<5;hh++) pj[hh]=__shfl(p[hh],j+u,64);
        #pragma unroll
        for(int j2=0;j2<5;j2++){
          acc[2*j2]  +=pj[j2]*bflo(wv[u][j2]);
          acc[2*j2+1]+=pj[j2]*bfhi(wv[u][j2]);
        }
      }
    }
    for(; j<c; j++){
      int sj=__shfl(s,j,64);
      float pj[5];
      #pragma unroll
      for(int hh=0;hh<5;hh++) pj[hh]=__shfl(p[hh],j,64);
      const u32* hr=(const u32*)(hb+(size_t)sj*HC+lane*10);
      #pragma unroll
      for(int j2=0;j2<5;j2++){
        u32 wv=hr[j2];
        acc[2*j2]  +=pj[j2]*bflo(wv);
        acc[2*j2+1]+=pj[j2]*bfhi(wv);
      }
    }
  }
  #pragma unroll
  for(int k=0;k<10;k++){
    int ccol=lane+64*k;
    float v=acc[k]/(den[k>>1]+1e-16f)+bias[ccol];
    if(RELU) v=fmaxf(v,0.f);
    if(WBF){
      ohi[(size_t)n*HC+ccol]=f2bf(v);
    }else{
      out[(size_t)n*HC+ccol]=v;
    }
  }
}

// ---------------- pooling + head ----------------

__global__ __launch_bounds__(256) void k_pool(const float* __restrict__ h, const float* __restrict__ wlin,
    const int* __restrict__ batch, float* __restrict__ ysum, float* __restrict__ cntg){
  int tid=threadIdx.x, lane=tid&63;
  int n=blockIdx.x*4+(tid>>6);
  if(n>=N_NODESC) return;
  float s=0.f;
  #pragma unroll
  for(int k=0;k<10;k++){ int c=lane+64*k; s+=h[(size_t)n*HC+c]*wlin[c]; }
  s=wred_sum(s);
  if(lane==0){
    int g=batch[n];
    atomicAdd(&ysum[g],s);
    atomicAdd(&cntg[g],1.f);
  }
}

__global__ void k_final(const float* __restrict__ ysum, const float* __restrict__ cntg,
                        const float* __restrict__ blin, float* __restrict__ out){
  int g=blockIdx.x*blockDim.x+threadIdx.x;
  if(g>=NGRAPH) return;
  out[g]=ysum[g]/fmaxf(cntg[g],1.f)+blin[0];
}

// ---------------- launch ----------------

extern "C" void kernel_launch(void* const* d_in, const int* in_sizes, int n_in,
                              void* d_out, int out_size, void* d_ws, size_t ws_size,
                              hipStream_t stream){
  const float* x     = (const float*)d_in[0];
  const float* eattr = (const float*)d_in[1];
  const float* W[3]    ={(const float*)d_in[2],(const float*)d_in[8],(const float*)d_in[14]};
  const float* We[3]   ={(const float*)d_in[3],(const float*)d_in[9],(const float*)d_in[15]};
  const float* asrc[3] ={(const float*)d_in[4],(const float*)d_in[10],(const float*)d_in[16]};
  const float* adst[3] ={(const float*)d_in[5],(const float*)d_in[11],(const float*)d_in[17]};
  const float* aedge[3]={(const float*)d_in[6],(const float*)d_in[12],(const float*)d_in[18]};
  const float* bias[3] ={(const float*)d_in[7],(const float*)d_in[13],(const float*)d_in[19]};
  const float* Wlin  = (const float*)d_in[20];
  const float* blin  = (const float*)d_in[21];
  const int* eind    = (const int*)d_in[22];
  const int* srcp    = eind;
  const int* dstp    = eind + N_EDGESC;
  const int* batch   = (const int*)d_in[23];
  float* out = (float*)d_out;

  char* ws=(char*)d_ws;
  size_t o=0;
  auto alloc=[&](size_t bytes)->void*{ void* p=ws+o; o=(o+bytes+255)&~(size_t)255; return p; };
  u16* hb   =(u16*)alloc((size_t)N_NODESC*HC*2);           // permuted bf16 h
  float* aggf =(float*)alloc((size_t)N_NODESC*HC*4);       // final layer f32 out
  u16* Ahi =(u16*)alloc((size_t)N_NODESC*HC*2);            // agg bf16 out (next GEMM A)
  u16* Axhi=(u16*)alloc((size_t)N_NODESC*64*2);            // converted x (KP=64)
  u16* Axlo=(u16*)alloc((size_t)N_NODESC*64*2);
  u16* Bthi=(u16*)alloc((size_t)HC*HC*2);                  // transposed weights
  u16* Btlo=(u16*)alloc((size_t)HC*HC*2);
  float* al   =(float*)alloc((size_t)N_NODESC*5*4);
  float* ar   =(float*)alloc((size_t)N_NODESC*5*4);
  float* ael  =(float*)alloc((size_t)N_NODESC*5*4);
  float* aeC  =(float*)alloc((size_t)N_EDGESC*5*4);
  float* lattr=(float*)alloc((size_t)N_NODESC*10*4);
  float* eattrC=(float*)alloc((size_t)N_EDGESC*10*4);
  float* ve   =(float*)alloc(64*4);
  float* ysum =(float*)alloc(512*4);
  float* cntg =(float*)alloc(512*4);
  int* cntI   =(int*)alloc((size_t)N_NODESC*4);
  int* rptr   =(int*)alloc((size_t)N_NODESC*4);
  int* pos    =(int*)alloc((size_t)N_NODESC*4);
  int* eidx   =(int*)alloc((size_t)N_EDGESC*4);
  int* srcE   =(int*)alloc((size_t)N_EDGESC*4);

  hipMemsetAsync(cntI,0,(size_t)N_NODESC*4,stream);
  hipMemsetAsync(ysum,0,512*4,stream);
  hipMemsetAsync(cntg,0,512*4,stream);

  k_count<<<(N_EDGESC+255)/256,256,0,stream>>>(dstp,cntI);
  k_scan<<<1,1024,0,stream>>>(cntI,rptr,pos);
  k_scatter<<<(N_EDGESC+255)/256,256,0,stream>>>(dstp,pos,eidx);
  k_csr_edges<<<(N_EDGESC+255)/256,256,0,stream>>>(eidx,srcp,eattr,srcE,eattrC);
  k_loop_attr<<<(N_NODESC+3)/4,256,0,stream>>>(eattrC,rptr,cntI,lattr);
  k_conv_x<<<(N_NODESC*64+255)/256,256,0,stream>>>(x,Axhi,Axlo);

  const int NBLK=5*((N_NODESC+127)/128);
  const int NEDGET=N_EDGESC+N_NODESC*5;
  for(int L=0;L<3;L++){
    int KL = (L==0)? 43 : HC;
    int KP = (L==0)? 64 : HC;
    k_ve<<<1,64,0,stream>>>(We[L],aedge[L],ve);
    k_conv_w<<<(HC*KP+255)/256,256,0,stream>>>(W[L],Bthi,Btlo,KL,KP);
    if(L==0)
      k_gemm_fused<3><<<NBLK,256,0,stream>>>(Axhi,Axlo,Bthi,Btlo,asrc[L],adst[L],hb,al,ar,N_NODESC,KP,NBLK);
    else
      k_gemm_fused<1><<<NBLK,256,0,stream>>>(Ahi,(const u16*)nullptr,Bthi,(const u16*)nullptr,asrc[L],adst[L],hb,al,ar,N_NODESC,KP,NBLK);
    k_edge_terms<<<(NEDGET+255)/256,256,0,stream>>>(eattrC,lattr,ve,aeC,ael);
    if(L<2)
      k_agg<true ,true ><<<(N_NODESC+3)/4,256,0,stream>>>(hb,srcE,rptr,cntI,al,ar,ael,aeC,bias[L],aggf,Ahi);
    else
      k_agg<false,false><<<(N_NODESC+3)/4,256,0,stream>>>(hb,srcE,rptr,cntI,al,ar,ael,aeC,bias[L],aggf,Ahi);
  }
  k_pool<<<(N_NODESC+3)/4,256,0,stream>>>(aggf,Wlin,batch,ysum,cntg);
  k_final<<<2,256,0,stream>>>(ysum,cntg,blin,out);
}

// Round 12
// 552.333 us; speedup vs baseline: 1.1020x; 1.0334x over previous
//
#include <hip/hip_runtime.h>

#define N_NODESC 20000
#define N_EDGESC 320000
#define HC 640
#define NGRAPH 500

typedef unsigned short u16;
typedef unsigned int u32;
typedef __attribute__((ext_vector_type(8))) short bf16x8;
typedef __attribute__((ext_vector_type(4))) float f32x4;

__device__ __forceinline__ float wred_sum(float v){
  #pragma unroll
  for(int o=32;o;o>>=1) v += __shfl_xor(v,o,64);
  return v;
}
__device__ __forceinline__ float lrelu(float x){ return x>0.f? x:0.2f*x; }

__device__ __forceinline__ u16 f2bf(float f){
  u32 u=__float_as_uint(f);
  u32 r=u+0x7FFFu+((u>>16)&1u);
  return (u16)(r>>16);
}
__device__ __forceinline__ float bf2f(u16 s){ return __uint_as_float(((u32)s)<<16); }
__device__ __forceinline__ float bflo(u32 w){ return __uint_as_float(w<<16); }
__device__ __forceinline__ float bfhi(u32 w){ return __uint_as_float(w&0xFFFF0000u); }

__device__ __forceinline__ void gload16(const void* g, void* l){
  __builtin_amdgcn_global_load_lds((const __attribute__((address_space(1))) void*)g,
                                   (__attribute__((address_space(3))) void*)l, 16, 0, 0);
}

// ---------------- graph preprocessing (layer-invariant) ----------------

__global__ void k_count(const int* __restrict__ dst, int* __restrict__ cnt){
  int i=blockIdx.x*blockDim.x+threadIdx.x;
  if(i>=N_EDGESC) return;
  atomicAdd(&cnt[dst[i]],1);
}

__global__ void k_scan(const int* __restrict__ cnt, int* __restrict__ rptr, int* __restrict__ pos){
  __shared__ int ps[1024];
  int t=threadIdx.x;
  const int CH=20;
  int beg=t*CH, end=min(beg+CH, N_NODESC);
  int s=0;
  for(int i=beg;i<end;i++) s+=cnt[i];
  ps[t]=s; __syncthreads();
  for(int off=1;off<1024;off<<=1){
    int v=(t>=off)? ps[t-off]:0;
    __syncthreads();
    ps[t]+=v;
    __syncthreads();
  }
  int base=ps[t]-s;
  for(int i=beg;i<end;i++){ rptr[i]=base; pos[i]=base; base+=cnt[i]; }
}

__global__ void k_scatter(const int* __restrict__ dst, int* __restrict__ pos, int* __restrict__ eidx){
  int i=blockIdx.x*blockDim.x+threadIdx.x;
  if(i>=N_EDGESC) return;
  int j=atomicAdd(&pos[dst[i]],1);
  eidx[j]=i;
}

// resolve CSR permutation ONCE: srcE[j]=src[eidx[j]], eattrC[j]=eattr[eidx[j]]
__global__ void k_csr_edges(const int* __restrict__ eidx, const int* __restrict__ src,
                            const float* __restrict__ eattr,
                            int* __restrict__ srcE, float* __restrict__ eattrC){
  int j=blockIdx.x*blockDim.x+threadIdx.x;
  if(j>=N_EDGESC) return;
  int e=eidx[j];
  srcE[j]=src[e];
  const float* ep=&eattr[(size_t)e*10];
  float* op=&eattrC[(size_t)j*10];
  #pragma unroll
  for(int k=0;k<10;k++) op[k]=ep[k];
}

// scatter-mean of edge_attr per dst node via CSR (linear reads); one wave per node
__global__ __launch_bounds__(256) void k_loop_attr(const float* __restrict__ eattrC,
    const int* __restrict__ rptr, const int* __restrict__ cnt,
    float* __restrict__ lattr){
  int tid=threadIdx.x, lane=tid&63;
  int n=blockIdx.x*4+(tid>>6);
  if(n>=N_NODESC) return;
  int beg=rptr[n], deg=cnt[n];
  float s[10]={0,0,0,0,0,0,0,0,0,0};
  for(int off=lane; off<deg; off+=64){
    const float* ep=&eattrC[(size_t)(beg+off)*10];
    #pragma unroll
    for(int k=0;k<10;k++) s[k]+=ep[k];
  }
  float inv=1.f/fmaxf((float)deg,1.f);
  #pragma unroll
  for(int k=0;k<10;k++){
    float tot=wred_sum(s[k]);
    if(lane==0) lattr[(size_t)n*10+k]=tot*inv;
  }
}

// ---------------- conversions ----------------

__global__ void k_conv_x(const float* __restrict__ x, u16* __restrict__ hi, u16* __restrict__ lo){
  int idx=blockIdx.x*blockDim.x+threadIdx.x;
  if(idx>=N_NODESC*64) return;
  int n=idx>>6, kk=idx&63;
  float v = kk<43 ? x[n*43+kk] : 0.f;
  u16 h=f2bf(v);
  hi[idx]=h; lo[idx]=f2bf(v-bf2f(h));
}

// all 3 layers' transposed weights in one launch.
// layout: L0 at off 0 (KP=64,KL=43), L1 at 640*64 (KP=640), L2 at 640*64+640*640.
__global__ void k_conv_w3(const float* __restrict__ W0, const float* __restrict__ W1,
                          const float* __restrict__ W2,
                          u16* __restrict__ hi, u16* __restrict__ lo){
  const int R0=HC*64, R1=R0+HC*HC;
  const int TOT=R1+HC*HC;
  int idx=blockIdx.x*blockDim.x+threadIdx.x;
  if(idx>=TOT) return;
  const float* W; int local, KP, KL, base;
  if(idx<R0){ W=W0; local=idx; KP=64; KL=43; base=0; }
  else if(idx<R1){ W=W1; local=idx-R0; KP=HC; KL=HC; base=R0; }
  else { W=W2; local=idx-R1; KP=HC; KL=HC; base=R1; }
  int n=local/KP, kk=local-n*KP;
  float v = kk<KL ? W[(size_t)kk*HC+n] : 0.f;
  u16 h=f2bf(v);
  hi[base+local]=h;
  lo[base+local]=f2bf(v-bf2f(h));
}

// ---------------- attention-term kernels (all hoisted) ----------------

// ve3[L][k][h] = sum_c We_L[k, h*128+c] * aedge_L[h*128+c]   (3 x 10 x 5)
__global__ void k_ve3(const float* __restrict__ We0, const float* __restrict__ ae0,
                      const float* __restrict__ We1, const float* __restrict__ ae1,
                      const float* __restrict__ We2, const float* __restrict__ ae2,
                      float* __restrict__ ve3){
  int t=threadIdx.x;
  if(t>=150) return;
  int L=t/50, r=t-50*L, k=r/5, h=r%5;
  const float* We = (L==0)?We0:(L==1)?We1:We2;
  const float* ae = (L==0)?ae0:(L==1)?ae1:ae2;
  float s=0.f;
  for(int c=0;c<128;c++) s += We[k*HC + h*128 + c]*ae[h*128+c];
  ve3[t]=s;
}

// all 3 layers: aeC3[L][j][h] for r<E ; ael3[L][n][h] for r>=E
__global__ __launch_bounds__(256) void k_edge_terms3(const float* __restrict__ eattrC,
    const float* __restrict__ lattr, const float* __restrict__ ve3,
    float* __restrict__ aeC3, float* __restrict__ ael3){
  __shared__ float ves[150];
  if(threadIdx.x<150) ves[threadIdx.x]=ve3[threadIdx.x];
  __syncthreads();
  const int NEDGET=N_EDGESC+N_NODESC*5;
  int idx=blockIdx.x*blockDim.x+threadIdx.x;
  if(idx>=3*NEDGET) return;
  int L=idx/NEDGET, r=idx-L*NEDGET;
  const float* vl=&ves[L*50];
  if(r<N_EDGESC){
    float ev[10];
    const float* ep=&eattrC[(size_t)r*10];
    #pragma unroll
    for(int k=0;k<10;k++) ev[k]=ep[k];
    #pragma unroll
    for(int hh=0;hh<5;hh++){
      float s=0.f;
      #pragma unroll
      for(int k=0;k<10;k++) s+=ev[k]*vl[k*5+hh];
      aeC3[(size_t)L*N_EDGESC*5 + (size_t)r*5+hh]=s;
    }
  }else{
    int t=r-N_EDGESC;
    int n=t/5, h=t-5*n;
    float s=0.f;
    #pragma unroll
    for(int k=0;k<10;k++) s+=lattr[(size_t)n*10+k]*vl[k*5+h];
    ael3[(size_t)L*N_NODESC*5 + t]=s;
  }
}

// ---------------- GEMM + nodeatt ----------------

// NT=3: C=Ahi@Bhi+Alo@Bhi+Ahi@Blo (layer 0, tiny K). NT=1: C=A@Bhi (pure bf16).
// BK=32, double-buffered LDS. NT=1: 32 KiB -> 5 blocks/CU.
template<int NT>
__global__ __launch_bounds__(256,(NT==1)?5:3) void k_gemm_fused(
    const u16* __restrict__ Ahi, const u16* __restrict__ Alo,
    const u16* __restrict__ Bhi, const u16* __restrict__ Blo,
    const float* __restrict__ asrc, const float* __restrict__ adst,
    u16* __restrict__ hb, float* __restrict__ al, float* __restrict__ ar,
    int M, int KP, int nblk){
  constexpr int TERMS=(NT==3)?4:2;
  constexpr int BOFF =(NT==3)?8192:4096;
  __shared__ u16 lds[2*TERMS*4096];
  int tid=threadIdx.x;
  int lane=tid&63;
  int w=tid>>6;
  int l15=lane&15, lg=lane>>4;
  int orig=blockIdx.x;
  int q=nblk>>3, r=nblk&7;
  int xcd=orig&7, off=orig>>3;
  int wg=(xcd<r? xcd*(q+1) : r*(q+1)+(xcd-r)*q)+off;
  int by=wg/5, bx=wg-5*by;
  int row0=by*128, col0=bx*128;
  int wr=w>>1, wc=w&1;

  f32x4 zero = {0.f,0.f,0.f,0.f};
  f32x4 acc[4][4];
  #pragma unroll
  for(int i=0;i<4;i++)
    #pragma unroll
    for(int j=0;j<4;j++) acc[i][j]=zero;

  auto stage=[&](int b, int k0){
    u16* base = lds + b*TERMS*4096;
    #pragma unroll
    for(int c=0;c<2;c++){
      int sb=w+4*c;
      int col=k0+lg*8;
      size_t aoff=(size_t)(row0+sb*16+l15)*KP + col;
      size_t boff=(size_t)(col0+sb*16+l15)*KP + col;
      gload16(Ahi+aoff, base + sb*512);
      if constexpr(NT==3) gload16(Alo+aoff, base+4096 + sb*512);
      gload16(Bhi+boff, base+BOFF + sb*512);
      if constexpr(NT==3) gload16(Blo+boff, base+BOFF+4096 + sb*512);
    }
  };

  int nt=KP/32;
  stage(0,0);
  __syncthreads();
  int cur=0;
  for(int t=0;t<nt;t++){
    if(t+1<nt) stage(cur^1,(t+1)*32);
    u16* cb = lds + cur*TERMS*4096;
    bf16x8 ah[4], bh[4];
    #pragma unroll
    for(int i=0;i<4;i++){
      ah[i]=*(const bf16x8*)&cb[(wr*4+i)*512 + lane*8];
      bh[i]=*(const bf16x8*)&cb[BOFF+(wc*4+i)*512 + lane*8];
    }
    if constexpr(NT==3){
      bf16x8 alv[4], bl[4];
      #pragma unroll
      for(int i=0;i<4;i++){
        alv[i]=*(const bf16x8*)&cb[4096+(wr*4+i)*512+lane*8];
        bl[i] =*(const bf16x8*)&cb[BOFF+4096+(wc*4+i)*512+lane*8];
      }
      #pragma unroll
      for(int i=0;i<4;i++)
        #pragma unroll
        for(int j=0;j<4;j++){
          acc[i][j]=__builtin_amdgcn_mfma_f32_16x16x32_bf16(ah[i], bh[j],acc[i][j],0,0,0);
          acc[i][j]=__builtin_amdgcn_mfma_f32_16x16x32_bf16(alv[i],bh[j],acc[i][j],0,0,0);
          acc[i][j]=__builtin_amdgcn_mfma_f32_16x16x32_bf16(ah[i], bl[j],acc[i][j],0,0,0);
        }
    }else{
      #pragma unroll
      for(int i=0;i<4;i++)
        #pragma unroll
        for(int j=0;j<4;j++)
          acc[i][j]=__builtin_amdgcn_mfma_f32_16x16x32_bf16(ah[i],bh[j],acc[i][j],0,0,0);
    }
    __syncthreads();
    cur^=1;
  }

  // ---- epilogue: hb (permuted bf16) + al/ar for head bx ----
  float asv[4], adv[4];
  #pragma unroll
  for(int j=0;j<4;j++){
    int c=col0+wc*64+j*16+l15;
    asv[j]=asrc[c]; adv[j]=adst[c];
  }
  #pragma unroll
  for(int i=0;i<4;i++){
    #pragma unroll
    for(int j=0;j<4;j++){
      #pragma unroll
      for(int rr=0;rr<4;rr++){
        int row=row0+wr*64+i*16+lg*4+rr;
        if(row<M) hb[(size_t)row*HC + (j*16+l15)*10 + bx*2+wc]=f2bf(acc[i][j][rr]);
      }
    }
  }
  float* redAl=(float*)lds;
  float* redAr=redAl+256;
  #pragma unroll
  for(int i=0;i<4;i++){
    #pragma unroll
    for(int rr=0;rr<4;rr++){
      float sa=0.f, sd=0.f;
      #pragma unroll
      for(int j=0;j<4;j++){ sa+=acc[i][j][rr]*asv[j]; sd+=acc[i][j][rr]*adv[j]; }
      #pragma unroll
      for(int o=1;o<16;o<<=1){ sa+=__shfl_xor(sa,o,64); sd+=__shfl_xor(sd,o,64); }
      if(l15==0){
        int lr=wr*64+i*16+lg*4+rr;
        redAl[lr*2+wc]=sa; redAr[lr*2+wc]=sd;
      }
    }
  }
  __syncthreads();
  if(tid<128){
    int row=row0+tid;
    if(row<M){
      al[(size_t)row*5+bx]=redAl[tid*2]+redAl[tid*2+1];
      ar[(size_t)row*5+bx]=redAr[tid*2]+redAr[tid*2+1];
    }
  }
}

// fused segment-softmax + aggregation; one wave per node. Direct-exp softmax
// (no max subtraction — shift-invariant, alpha is O(1) here). Linear CSR edge
// data; 8-deep unrolled hb row gather.
// WBF: write bf16 (next GEMM A). POOL: fused global-mean-pool partial dot.
template<bool RELU, bool WBF, bool POOL>
__global__ __launch_bounds__(256) void k_agg(const u16* __restrict__ hb, const int* __restrict__ srcE,
    const int* __restrict__ rptr, const int* __restrict__ cnt,
    const float* __restrict__ al, const float* __restrict__ ar, const float* __restrict__ ael,
    const float* __restrict__ aeC, const float* __restrict__ bias,
    u16* __restrict__ ohi,
    const float* __restrict__ wlin, const int* __restrict__ batch,
    float* __restrict__ ysum, float* __restrict__ cntg){
  int tid=threadIdx.x, lane=tid&63;
  int n=blockIdx.x*4+(tid>>6);
  if(n>=N_NODESC) return;
  float arn[5], den[5], acc[10];
  #pragma unroll
  for(int hh=0;hh<5;hh++) arn[hh]=ar[n*5+hh];
  float p0[5];
  #pragma unroll
  for(int hh=0;hh<5;hh++){
    p0[hh]=__expf(lrelu(al[n*5+hh]+arn[hh]+ael[n*5+hh]));   // self-loop weight
    den[hh]=p0[hh];
  }
  {
    const u32* sp=(const u32*)(hb+(size_t)n*HC+lane*10);
    #pragma unroll
    for(int j2=0;j2<5;j2++){
      u32 wv=sp[j2];
      acc[2*j2]  =p0[j2]*bflo(wv);
      acc[2*j2+1]=p0[j2]*bfhi(wv);
    }
  }
  int beg=rptr[n], deg=cnt[n];
  for(int off0=0; off0<deg; off0+=64){
    int c=min(64,deg-off0);
    bool valid = lane<c;
    int s=0; float p[5];
    #pragma unroll
    for(int hh=0;hh<5;hh++) p[hh]=0.f;
    if(valid){
      int j=beg+off0+lane;
      s=srcE[j];
      const float* av=&aeC[(size_t)j*5];
      #pragma unroll
      for(int hh=0;hh<5;hh++) p[hh]=__expf(lrelu(al[s*5+hh]+arn[hh]+av[hh]));
    }
    #pragma unroll
    for(int hh=0;hh<5;hh++) den[hh]+=wred_sum(p[hh]);
    int j=0;
    for(; j+7<c; j+=8){
      int sjv[8];
      #pragma unroll
      for(int u=0;u<8;u++) sjv[u]=__shfl(s,j+u,64);
      u32 wv[8][5];
      #pragma unroll
      for(int u=0;u<8;u++){
        const u32* hr=(const u32*)(hb+(size_t)sjv[u]*HC+lane*10);
        #pragma unroll
        for(int j2=0;j2<5;j2++) wv[u][j2]=hr[j2];
      }
      #pragma unroll
      for(int u=0;u<8;u++){
        float pj[5];
        #pragma unroll
        for(int hh=0;hh<5;hh++) pj[hh]=__shfl(p[hh],j+u,64);
        #pragma unroll
        for(int j2=0;j2<5;j2++){
          acc[2*j2]  +=pj[j2]*bflo(wv[u][j2]);
          acc[2*j2+1]+=pj[j2]*bfhi(wv[u][j2]);
        }
      }
    }
    for(; j<c; j++){
      int sj=__shfl(s,j,64);
      float pj[5];
      #pragma unroll
      for(int hh=0;hh<5;hh++) pj[hh]=__shfl(p[hh],j,64);
      const u32* hr=(const u32*)(hb+(size_t)sj*HC+lane*10);
      #pragma unroll
      for(int j2=0;j2<5;j2++){
        u32 wv=hr[j2];
        acc[2*j2]  +=pj[j2]*bflo(wv);
        acc[2*j2+1]+=pj[j2]*bfhi(wv);
      }
    }
  }
  float v[10];
  #pragma unroll
  for(int k=0;k<10;k++){
    int ccol=lane+64*k;
    float vv=acc[k]/(den[k>>1]+1e-16f)+bias[ccol];
    if(RELU) vv=fmaxf(vv,0.f);
    v[k]=vv;
    if(WBF) ohi[(size_t)n*HC+ccol]=f2bf(vv);
  }
  if(POOL){
    float s=0.f;
    #pragma unroll
    for(int k=0;k<10;k++) s+=v[k]*wlin[lane+64*k];
    s=wred_sum(s);
    if(lane==0){
      int g=batch[n];
      atomicAdd(&ysum[g],s);
      atomicAdd(&cntg[g],1.f);
    }
  }
}

__global__ void k_final(const float* __restrict__ ysum, const float* __restrict__ cntg,
                        const float* __restrict__ blin, float* __restrict__ out){
  int g=blockIdx.x*blockDim.x+threadIdx.x;
  if(g>=NGRAPH) return;
  out[g]=ysum[g]/fmaxf(cntg[g],1.f)+blin[0];
}

// ---------------- launch ----------------

extern "C" void kernel_launch(void* const* d_in, const int* in_sizes, int n_in,
                              void* d_out, int out_size, void* d_ws, size_t ws_size,
                              hipStream_t stream){
  const float* x     = (const float*)d_in[0];
  const float* eattr = (const float*)d_in[1];
  const float* W[3]    ={(const float*)d_in[2],(const float*)d_in[8],(const float*)d_in[14]};
  const float* We[3]   ={(const float*)d_in[3],(const float*)d_in[9],(const float*)d_in[15]};
  const float* asrc[3] ={(const float*)d_in[4],(const float*)d_in[10],(const float*)d_in[16]};
  const float* adst[3] ={(const float*)d_in[5],(const float*)d_in[11],(const float*)d_in[17]};
  const float* aedge[3]={(const float*)d_in[6],(const float*)d_in[12],(const float*)d_in[18]};
  const float* bias[3] ={(const float*)d_in[7],(const float*)d_in[13],(const float*)d_in[19]};
  const float* Wlin  = (const float*)d_in[20];
  const float* blin  = (const float*)d_in[21];
  const int* eind    = (const int*)d_in[22];
  const int* srcp    = eind;
  const int* dstp    = eind + N_EDGESC;
  const int* batch   = (const int*)d_in[23];
  float* out = (float*)d_out;

  char* ws=(char*)d_ws;
  size_t o=0;
  auto alloc=[&](size_t bytes)->void*{ void* p=ws+o; o=(o+bytes+255)&~(size_t)255; return p; };
  u16* hb   =(u16*)alloc((size_t)N_NODESC*HC*2);           // permuted bf16 h
  u16* Ahi =(u16*)alloc((size_t)N_NODESC*HC*2);            // agg bf16 out (next GEMM A)
  u16* Axhi=(u16*)alloc((size_t)N_NODESC*64*2);            // converted x (KP=64)
  u16* Axlo=(u16*)alloc((size_t)N_NODESC*64*2);
  const int WB0=0, WB1=HC*64, WB2=WB1+HC*HC;               // packed Bt offsets
  u16* Bthi3=(u16*)alloc((size_t)(WB2+HC*HC)*2);
  u16* Btlo3=(u16*)alloc((size_t)(WB2+HC*HC)*2);
  float* al   =(float*)alloc((size_t)N_NODESC*5*4);
  float* ar   =(float*)alloc((size_t)N_NODESC*5*4);
  float* ael3 =(float*)alloc((size_t)3*N_NODESC*5*4);
  float* aeC3 =(float*)alloc((size_t)3*N_EDGESC*5*4);
  float* lattr=(float*)alloc((size_t)N_NODESC*10*4);
  float* eattrC=(float*)alloc((size_t)N_EDGESC*10*4);
  float* ve3  =(float*)alloc(256*4);
  float* ysum =(float*)alloc(512*4);
  float* cntg =(float*)alloc(512*4);
  int* cntI   =(int*)alloc((size_t)N_NODESC*4);
  int* rptr   =(int*)alloc((size_t)N_NODESC*4);
  int* pos    =(int*)alloc((size_t)N_NODESC*4);
  int* eidx   =(int*)alloc((size_t)N_EDGESC*4);
  int* srcE   =(int*)alloc((size_t)N_EDGESC*4);

  hipMemsetAsync(cntI,0,(size_t)N_NODESC*4,stream);
  hipMemsetAsync(ysum,0,512*4,stream);
  hipMemsetAsync(cntg,0,512*4,stream);

  k_count<<<(N_EDGESC+255)/256,256,0,stream>>>(dstp,cntI);
  k_scan<<<1,1024,0,stream>>>(cntI,rptr,pos);
  k_scatter<<<(N_EDGESC+255)/256,256,0,stream>>>(dstp,pos,eidx);
  k_csr_edges<<<(N_EDGESC+255)/256,256,0,stream>>>(eidx,srcp,eattr,srcE,eattrC);
  k_loop_attr<<<(N_NODESC+3)/4,256,0,stream>>>(eattrC,rptr,cntI,lattr);
  k_conv_x<<<(N_NODESC*64+255)/256,256,0,stream>>>(x,Axhi,Axlo);
  k_ve3<<<1,256,0,stream>>>(We[0],aedge[0],We[1],aedge[1],We[2],aedge[2],ve3);
  {
    int tot=WB2+HC*HC;
    k_conv_w3<<<(tot+255)/256,256,0,stream>>>(W[0],W[1],W[2],Bthi3,Btlo3);
  }
  {
    const int NEDGET=N_EDGESC+N_NODESC*5;
    k_edge_terms3<<<(3*NEDGET+255)/256,256,0,stream>>>(eattrC,lattr,ve3,aeC3,ael3);
  }

  const int NBLK=5*((N_NODESC+127)/128);
  const int WBo[3]={WB0,WB1,WB2};
  for(int L=0;L<3;L++){
    int KP = (L==0)? 64 : HC;
    if(L==0)
      k_gemm_fused<3><<<NBLK,256,0,stream>>>(Axhi,Axlo,Bthi3+WBo[L],Btlo3+WBo[L],asrc[L],adst[L],hb,al,ar,N_NODESC,KP,NBLK);
    else
      k_gemm_fused<1><<<NBLK,256,0,stream>>>(Ahi,(const u16*)nullptr,Bthi3+WBo[L],(const u16*)nullptr,asrc[L],adst[L],hb,al,ar,N_NODESC,KP,NBLK);
    const float* aeL = aeC3 + (size_t)L*N_EDGESC*5;
    const float* aelL= ael3 + (size_t)L*N_NODESC*5;
    if(L==0)
      k_agg<true ,true ,false><<<(N_NODESC+3)/4,256,0,stream>>>(hb,srcE,rptr,cntI,al,ar,aelL,aeL,bias[L],Ahi,Wlin,batch,ysum,cntg);
    else if(L==1)
      k_agg<true ,true ,false><<<(N_NODESC+3)/4,256,0,stream>>>(hb,srcE,rptr,cntI,al,ar,aelL,aeL,bias[L],Ahi,Wlin,batch,ysum,cntg);
    else
      k_agg<false,false,true ><<<(N_NODESC+3)/4,256,0,stream>>>(hb,srcE,rptr,cntI,al,ar,aelL,aeL,bias[L],Ahi,Wlin,batch,ysum,cntg);
  }
  k_final<<<2,256,0,stream>>>(ysum,cntg,blin,out);
}

// Round 13
// 529.158 us; speedup vs baseline: 1.1502x; 1.0438x over previous
//
#include <hip/hip_runtime.h>

#define N_NODESC 20000
#define N_EDGESC 320000
#define HC 640
#define NGRAPH 500

typedef unsigned short u16;
typedef unsigned int u32;
typedef __attribute__((ext_vector_type(8))) short bf16x8;
typedef __attribute__((ext_vector_type(4))) float f32x4;

__device__ __forceinline__ float wred_sum(float v){
  #pragma unroll
  for(int o=32;o;o>>=1) v += __shfl_xor(v,o,64);
  return v;
}
__device__ __forceinline__ float lrelu(float x){ return x>0.f? x:0.2f*x; }

__device__ __forceinline__ u16 f2bf(float f){
  u32 u=__float_as_uint(f);
  u32 r=u+0x7FFFu+((u>>16)&1u);
  return (u16)(r>>16);
}
__device__ __forceinline__ float bf2f(u16 s){ return __uint_as_float(((u32)s)<<16); }
__device__ __forceinline__ float bflo(u32 w){ return __uint_as_float(w<<16); }
__device__ __forceinline__ float bfhi(u32 w){ return __uint_as_float(w&0xFFFF0000u); }

__device__ __forceinline__ void gload16(const void* g, void* l){
  __builtin_amdgcn_global_load_lds((const __attribute__((address_space(1))) void*)g,
                                   (__attribute__((address_space(3))) void*)l, 16, 0, 0);
}

// ---------------- graph preprocessing (layer-invariant) ----------------

__global__ void k_count(const int* __restrict__ dst, int* __restrict__ cnt){
  int i=blockIdx.x*blockDim.x+threadIdx.x;
  if(i>=N_EDGESC) return;
  atomicAdd(&cnt[dst[i]],1);
}

__global__ void k_scan(const int* __restrict__ cnt, int* __restrict__ rptr, int* __restrict__ pos){
  __shared__ int ps[1024];
  int t=threadIdx.x;
  const int CH=20;
  int beg=t*CH, end=min(beg+CH, N_NODESC);
  int s=0;
  for(int i=beg;i<end;i++) s+=cnt[i];
  ps[t]=s; __syncthreads();
  for(int off=1;off<1024;off<<=1){
    int v=(t>=off)? ps[t-off]:0;
    __syncthreads();
    ps[t]+=v;
    __syncthreads();
  }
  int base=ps[t]-s;
  for(int i=beg;i<end;i++){ rptr[i]=base; pos[i]=base; base+=cnt[i]; }
}

__global__ void k_scatter(const int* __restrict__ dst, int* __restrict__ pos, int* __restrict__ eidx){
  int i=blockIdx.x*blockDim.x+threadIdx.x;
  if(i>=N_EDGESC) return;
  int j=atomicAdd(&pos[dst[i]],1);
  eidx[j]=i;
}

// resolve CSR permutation ONCE: srcE[j]=src[eidx[j]], eattrC[j]=eattr[eidx[j]]
__global__ void k_csr_edges(const int* __restrict__ eidx, const int* __restrict__ src,
                            const float* __restrict__ eattr,
                            int* __restrict__ srcE, float* __restrict__ eattrC){
  int j=blockIdx.x*blockDim.x+threadIdx.x;
  if(j>=N_EDGESC) return;
  int e=eidx[j];
  srcE[j]=src[e];
  const float* ep=&eattr[(size_t)e*10];
  float* op=&eattrC[(size_t)j*10];
  #pragma unroll
  for(int k=0;k<10;k++) op[k]=ep[k];
}

// scatter-mean of edge_attr per dst node via CSR (linear reads); one wave per node
__global__ __launch_bounds__(256) void k_loop_attr(const float* __restrict__ eattrC,
    const int* __restrict__ rptr, const int* __restrict__ cnt,
    float* __restrict__ lattr){
  int tid=threadIdx.x, lane=tid&63;
  int n=blockIdx.x*4+(tid>>6);
  if(n>=N_NODESC) return;
  int beg=rptr[n], deg=cnt[n];
  float s[10]={0,0,0,0,0,0,0,0,0,0};
  for(int off=lane; off<deg; off+=64){
    const float* ep=&eattrC[(size_t)(beg+off)*10];
    #pragma unroll
    for(int k=0;k<10;k++) s[k]+=ep[k];
  }
  float inv=1.f/fmaxf((float)deg,1.f);
  #pragma unroll
  for(int k=0;k<10;k++){
    float tot=wred_sum(s[k]);
    if(lane==0) lattr[(size_t)n*10+k]=tot*inv;
  }
}

// ---------------- conversions ----------------

__global__ void k_conv_x(const float* __restrict__ x, u16* __restrict__ hi, u16* __restrict__ lo){
  int idx=blockIdx.x*blockDim.x+threadIdx.x;
  if(idx>=N_NODESC*64) return;
  int n=idx>>6, kk=idx&63;
  float v = kk<43 ? x[n*43+kk] : 0.f;
  u16 h=f2bf(v);
  hi[idx]=h; lo[idx]=f2bf(v-bf2f(h));
}

// all 3 layers' transposed weights in one launch.
__global__ void k_conv_w3(const float* __restrict__ W0, const float* __restrict__ W1,
                          const float* __restrict__ W2,
                          u16* __restrict__ hi, u16* __restrict__ lo){
  const int R0=HC*64, R1=R0+HC*HC;
  const int TOT=R1+HC*HC;
  int idx=blockIdx.x*blockDim.x+threadIdx.x;
  if(idx>=TOT) return;
  const float* W; int local, KP, KL, base;
  if(idx<R0){ W=W0; local=idx; KP=64; KL=43; base=0; }
  else if(idx<R1){ W=W1; local=idx-R0; KP=HC; KL=HC; base=R0; }
  else { W=W2; local=idx-R1; KP=HC; KL=HC; base=R1; }
  int n=local/KP, kk=local-n*KP;
  float v = kk<KL ? W[(size_t)kk*HC+n] : 0.f;
  u16 h=f2bf(v);
  hi[base+local]=h;
  lo[base+local]=f2bf(v-bf2f(h));
}

// ---------------- attention-term kernels (all hoisted) ----------------

__global__ void k_ve3(const float* __restrict__ We0, const float* __restrict__ ae0,
                      const float* __restrict__ We1, const float* __restrict__ ae1,
                      const float* __restrict__ We2, const float* __restrict__ ae2,
                      float* __restrict__ ve3){
  int t=threadIdx.x;
  if(t>=150) return;
  int L=t/50, r=t-50*L, k=r/5, h=r%5;
  const float* We = (L==0)?We0:(L==1)?We1:We2;
  const float* ae = (L==0)?ae0:(L==1)?ae1:ae2;
  float s=0.f;
  for(int c=0;c<128;c++) s += We[k*HC + h*128 + c]*ae[h*128+c];
  ve3[t]=s;
}

// all 3 layers: aeC3[L][j][h] for r<E ; ael3[L][n][h] for r>=E
__global__ __launch_bounds__(256) void k_edge_terms3(const float* __restrict__ eattrC,
    const float* __restrict__ lattr, const float* __restrict__ ve3,
    float* __restrict__ aeC3, float* __restrict__ ael3){
  __shared__ float ves[150];
  if(threadIdx.x<150) ves[threadIdx.x]=ve3[threadIdx.x];
  __syncthreads();
  const int NEDGET=N_EDGESC+N_NODESC*5;
  int idx=blockIdx.x*blockDim.x+threadIdx.x;
  if(idx>=3*NEDGET) return;
  int L=idx/NEDGET, r=idx-L*NEDGET;
  const float* vl=&ves[L*50];
  if(r<N_EDGESC){
    float ev[10];
    const float* ep=&eattrC[(size_t)r*10];
    #pragma unroll
    for(int k=0;k<10;k++) ev[k]=ep[k];
    #pragma unroll
    for(int hh=0;hh<5;hh++){
      float s=0.f;
      #pragma unroll
      for(int k=0;k<10;k++) s+=ev[k]*vl[k*5+hh];
      aeC3[(size_t)L*N_EDGESC*5 + (size_t)r*5+hh]=s;
    }
  }else{
    int t=r-N_EDGESC;
    int n=t/5, h=t-5*n;
    float s=0.f;
    #pragma unroll
    for(int k=0;k<10;k++) s+=lattr[(size_t)n*10+k]*vl[k*5+h];
    ael3[(size_t)L*N_NODESC*5 + t]=s;
  }
}

// ---------------- GEMM + nodeatt ----------------

// NT=3: C=Ahi@Bhi+Alo@Bhi+Ahi@Blo (layer 0, tiny K). NT=1: C=A@Bhi (pure bf16).
// BK=32, double-buffered LDS. NT=1: 32 KiB -> 5 blocks/CU.
template<int NT>
__global__ __launch_bounds__(256,(NT==1)?5:3) void k_gemm_fused(
    const u16* __restrict__ Ahi, const u16* __restrict__ Alo,
    const u16* __restrict__ Bhi, const u16* __restrict__ Blo,
    const float* __restrict__ asrc, const float* __restrict__ adst,
    u16* __restrict__ hb, float* __restrict__ al, float* __restrict__ ar,
    int M, int KP, int nblk){
  constexpr int TERMS=(NT==3)?4:2;
  constexpr int BOFF =(NT==3)?8192:4096;
  __shared__ u16 lds[2*TERMS*4096];
  int tid=threadIdx.x;
  int lane=tid&63;
  int w=tid>>6;
  int l15=lane&15, lg=lane>>4;
  int orig=blockIdx.x;
  int q=nblk>>3, r=nblk&7;
  int xcd=orig&7, off=orig>>3;
  int wg=(xcd<r? xcd*(q+1) : r*(q+1)+(xcd-r)*q)+off;
  int by=wg/5, bx=wg-5*by;
  int row0=by*128, col0=bx*128;
  int wr=w>>1, wc=w&1;

  f32x4 zero = {0.f,0.f,0.f,0.f};
  f32x4 acc[4][4];
  #pragma unroll
  for(int i=0;i<4;i++)
    #pragma unroll
    for(int j=0;j<4;j++) acc[i][j]=zero;

  auto stage=[&](int b, int k0){
    u16* base = lds + b*TERMS*4096;
    #pragma unroll
    for(int c=0;c<2;c++){
      int sb=w+4*c;
      int col=k0+lg*8;
      size_t aoff=(size_t)(row0+sb*16+l15)*KP + col;
      size_t boff=(size_t)(col0+sb*16+l15)*KP + col;
      gload16(Ahi+aoff, base + sb*512);
      if constexpr(NT==3) gload16(Alo+aoff, base+4096 + sb*512);
      gload16(Bhi+boff, base+BOFF + sb*512);
      if constexpr(NT==3) gload16(Blo+boff, base+BOFF+4096 + sb*512);
    }
  };

  int nt=KP/32;
  stage(0,0);
  __syncthreads();
  int cur=0;
  for(int t=0;t<nt;t++){
    if(t+1<nt) stage(cur^1,(t+1)*32);
    u16* cb = lds + cur*TERMS*4096;
    bf16x8 ah[4], bh[4];
    #pragma unroll
    for(int i=0;i<4;i++){
      ah[i]=*(const bf16x8*)&cb[(wr*4+i)*512 + lane*8];
      bh[i]=*(const bf16x8*)&cb[BOFF+(wc*4+i)*512 + lane*8];
    }
    if constexpr(NT==3){
      bf16x8 alv[4], bl[4];
      #pragma unroll
      for(int i=0;i<4;i++){
        alv[i]=*(const bf16x8*)&cb[4096+(wr*4+i)*512+lane*8];
        bl[i] =*(const bf16x8*)&cb[BOFF+4096+(wc*4+i)*512+lane*8];
      }
      #pragma unroll
      for(int i=0;i<4;i++)
        #pragma unroll
        for(int j=0;j<4;j++){
          acc[i][j]=__builtin_amdgcn_mfma_f32_16x16x32_bf16(ah[i], bh[j],acc[i][j],0,0,0);
          acc[i][j]=__builtin_amdgcn_mfma_f32_16x16x32_bf16(alv[i],bh[j],acc[i][j],0,0,0);
          acc[i][j]=__builtin_amdgcn_mfma_f32_16x16x32_bf16(ah[i], bl[j],acc[i][j],0,0,0);
        }
    }else{
      #pragma unroll
      for(int i=0;i<4;i++)
        #pragma unroll
        for(int j=0;j<4;j++)
          acc[i][j]=__builtin_amdgcn_mfma_f32_16x16x32_bf16(ah[i],bh[j],acc[i][j],0,0,0);
    }
    __syncthreads();
    cur^=1;
  }

  // ---- epilogue: hb (permuted bf16) + al/ar for head bx ----
  float asv[4], adv[4];
  #pragma unroll
  for(int j=0;j<4;j++){
    int c=col0+wc*64+j*16+l15;
    asv[j]=asrc[c]; adv[j]=adst[c];
  }
  #pragma unroll
  for(int i=0;i<4;i++){
    #pragma unroll
    for(int j=0;j<4;j++){
      #pragma unroll
      for(int rr=0;rr<4;rr++){
        int row=row0+wr*64+i*16+lg*4+rr;
        if(row<M) hb[(size_t)row*HC + (j*16+l15)*10 + bx*2+wc]=f2bf(acc[i][j][rr]);
      }
    }
  }
  float* redAl=(float*)lds;
  float* redAr=redAl+256;
  #pragma unroll
  for(int i=0;i<4;i++){
    #pragma unroll
    for(int rr=0;rr<4;rr++){
      float sa=0.f, sd=0.f;
      #pragma unroll
      for(int j=0;j<4;j++){ sa+=acc[i][j][rr]*asv[j]; sd+=acc[i][j][rr]*adv[j]; }
      #pragma unroll
      for(int o=1;o<16;o<<=1){ sa+=__shfl_xor(sa,o,64); sd+=__shfl_xor(sd,o,64); }
      if(l15==0){
        int lr=wr*64+i*16+lg*4+rr;
        redAl[lr*2+wc]=sa; redAr[lr*2+wc]=sd;
      }
    }
  }
  __syncthreads();
  if(tid<128){
    int row=row0+tid;
    if(row<M){
      al[(size_t)row*5+bx]=redAl[tid*2]+redAl[tid*2+1];
      ar[(size_t)row*5+bx]=redAr[tid*2]+redAr[tid*2+1];
    }
  }
}

// fused segment-softmax + aggregation; one wave per node. Direct-exp softmax.
// WBF: write bf16 (next GEMM A). POOL: atomic-free per-node pooled dot -> pnode.
template<bool RELU, bool WBF, bool POOL>
__global__ __launch_bounds__(256) void k_agg(const u16* __restrict__ hb, const int* __restrict__ srcE,
    const int* __restrict__ rptr, const int* __restrict__ cnt,
    const float* __restrict__ al, const float* __restrict__ ar, const float* __restrict__ ael,
    const float* __restrict__ aeC, const float* __restrict__ bias,
    u16* __restrict__ ohi,
    const float* __restrict__ wlin, float* __restrict__ pnode){
  int tid=threadIdx.x, lane=tid&63;
  int n=blockIdx.x*4+(tid>>6);
  if(n>=N_NODESC) return;
  float arn[5], den[5], acc[10];
  #pragma unroll
  for(int hh=0;hh<5;hh++) arn[hh]=ar[n*5+hh];
  float p0[5];
  #pragma unroll
  for(int hh=0;hh<5;hh++){
    p0[hh]=__expf(lrelu(al[n*5+hh]+arn[hh]+ael[n*5+hh]));   // self-loop weight
    den[hh]=p0[hh];
  }
  {
    const u32* sp=(const u32*)(hb+(size_t)n*HC+lane*10);
    #pragma unroll
    for(int j2=0;j2<5;j2++){
      u32 wv=sp[j2];
      acc[2*j2]  =p0[j2]*bflo(wv);
      acc[2*j2+1]=p0[j2]*bfhi(wv);
    }
  }
  int beg=rptr[n], deg=cnt[n];
  for(int off0=0; off0<deg; off0+=64){
    int c=min(64,deg-off0);
    bool valid = lane<c;
    int s=0; float p[5];
    #pragma unroll
    for(int hh=0;hh<5;hh++) p[hh]=0.f;
    if(valid){
      int j=beg+off0+lane;
      s=srcE[j];
      const float* av=&aeC[(size_t)j*5];
      #pragma unroll
      for(int hh=0;hh<5;hh++) p[hh]=__expf(lrelu(al[s*5+hh]+arn[hh]+av[hh]));
    }
    #pragma unroll
    for(int hh=0;hh<5;hh++) den[hh]+=wred_sum(p[hh]);
    int j=0;
    for(; j+7<c; j+=8){
      int sjv[8];
      #pragma unroll
      for(int u=0;u<8;u++) sjv[u]=__shfl(s,j+u,64);
      u32 wv[8][5];
      #pragma unroll
      for(int u=0;u<8;u++){
        const u32* hr=(const u32*)(hb+(size_t)sjv[u]*HC+lane*10);
        #pragma unroll
        for(int j2=0;j2<5;j2++) wv[u][j2]=hr[j2];
      }
      #pragma unroll
      for(int u=0;u<8;u++){
        float pj[5];
        #pragma unroll
        for(int hh=0;hh<5;hh++) pj[hh]=__shfl(p[hh],j+u,64);
        #pragma unroll
        for(int j2=0;j2<5;j2++){
          acc[2*j2]  +=pj[j2]*bflo(wv[u][j2]);
          acc[2*j2+1]+=pj[j2]*bfhi(wv[u][j2]);
        }
      }
    }
    for(; j<c; j++){
      int sj=__shfl(s,j,64);
      float pj[5];
      #pragma unroll
      for(int hh=0;hh<5;hh++) pj[hh]=__shfl(p[hh],j,64);
      const u32* hr=(const u32*)(hb+(size_t)sj*HC+lane*10);
      #pragma unroll
      for(int j2=0;j2<5;j2++){
        u32 wv=hr[j2];
        acc[2*j2]  +=pj[j2]*bflo(wv);
        acc[2*j2+1]+=pj[j2]*bfhi(wv);
      }
    }
  }
  float v[10];
  #pragma unroll
  for(int k=0;k<10;k++){
    int ccol=lane+64*k;
    float vv=acc[k]/(den[k>>1]+1e-16f)+bias[ccol];
    if(RELU) vv=fmaxf(vv,0.f);
    v[k]=vv;
    if(WBF) ohi[(size_t)n*HC+ccol]=f2bf(vv);
  }
  if(POOL){
    float s=0.f;
    #pragma unroll
    for(int k=0;k<10;k++) s+=v[k]*wlin[lane+64*k];
    s=wred_sum(s);
    if(lane==0) pnode[n]=s;
  }
}

// per-graph mean over sorted batch segments (binary search, no atomics);
// one wave per graph, writes final output.
__global__ __launch_bounds__(256) void k_graphout(const float* __restrict__ pnode,
    const int* __restrict__ batch, const float* __restrict__ blin,
    float* __restrict__ out){
  int tid=threadIdx.x, lane=tid&63;
  int g=blockIdx.x*4+(tid>>6);
  if(g>=NGRAPH) return;
  auto lb=[&](int val){
    int lo=0, hi=N_NODESC;
    while(lo<hi){ int mid=(lo+hi)>>1; if(batch[mid]<val) lo=mid+1; else hi=mid; }
    return lo;
  };
  int s0=lb(g), s1=lb(g+1);
  float s=0.f;
  for(int i=s0+lane;i<s1;i+=64) s+=pnode[i];
  s=wred_sum(s);
  if(lane==0) out[g]=s/fmaxf((float)(s1-s0),1.f)+blin[0];
}

// ---------------- launch ----------------

extern "C" void kernel_launch(void* const* d_in, const int* in_sizes, int n_in,
                              void* d_out, int out_size, void* d_ws, size_t ws_size,
                              hipStream_t stream){
  const float* x     = (const float*)d_in[0];
  const float* eattr = (const float*)d_in[1];
  const float* W[3]    ={(const float*)d_in[2],(const float*)d_in[8],(const float*)d_in[14]};
  const float* We[3]   ={(const float*)d_in[3],(const float*)d_in[9],(const float*)d_in[15]};
  const float* asrc[3] ={(const float*)d_in[4],(const float*)d_in[10],(const float*)d_in[16]};
  const float* adst[3] ={(const float*)d_in[5],(const float*)d_in[11],(const float*)d_in[17]};
  const float* aedge[3]={(const float*)d_in[6],(const float*)d_in[12],(const float*)d_in[18]};
  const float* bias[3] ={(const float*)d_in[7],(const float*)d_in[13],(const float*)d_in[19]};
  const float* Wlin  = (const float*)d_in[20];
  const float* blin  = (const float*)d_in[21];
  const int* eind    = (const int*)d_in[22];
  const int* srcp    = eind;
  const int* dstp    = eind + N_EDGESC;
  const int* batch   = (const int*)d_in[23];
  float* out = (float*)d_out;

  char* ws=(char*)d_ws;
  size_t o=0;
  auto alloc=[&](size_t bytes)->void*{ void* p=ws+o; o=(o+bytes+255)&~(size_t)255; return p; };
  u16* hb   =(u16*)alloc((size_t)N_NODESC*HC*2);           // permuted bf16 h
  u16* Ahi =(u16*)alloc((size_t)N_NODESC*HC*2);            // agg bf16 out (next GEMM A)
  u16* Axhi=(u16*)alloc((size_t)N_NODESC*64*2);            // converted x (KP=64)
  u16* Axlo=(u16*)alloc((size_t)N_NODESC*64*2);
  const int WB0=0, WB1=HC*64, WB2=WB1+HC*HC;               // packed Bt offsets
  u16* Bthi3=(u16*)alloc((size_t)(WB2+HC*HC)*2);
  u16* Btlo3=(u16*)alloc((size_t)(WB2+HC*HC)*2);
  float* al   =(float*)alloc((size_t)N_NODESC*5*4);
  float* ar   =(float*)alloc((size_t)N_NODESC*5*4);
  float* ael3 =(float*)alloc((size_t)3*N_NODESC*5*4);
  float* aeC3 =(float*)alloc((size_t)3*N_EDGESC*5*4);
  float* lattr=(float*)alloc((size_t)N_NODESC*10*4);
  float* eattrC=(float*)alloc((size_t)N_EDGESC*10*4);
  float* ve3  =(float*)alloc(256*4);
  float* pnode=(float*)alloc((size_t)N_NODESC*4);
  int* cntI   =(int*)alloc((size_t)N_NODESC*4);
  int* rptr   =(int*)alloc((size_t)N_NODESC*4);
  int* pos    =(int*)alloc((size_t)N_NODESC*4);
  int* eidx   =(int*)alloc((size_t)N_EDGESC*4);
  int* srcE   =(int*)alloc((size_t)N_EDGESC*4);

  hipMemsetAsync(cntI,0,(size_t)N_NODESC*4,stream);

  k_count<<<(N_EDGESC+255)/256,256,0,stream>>>(dstp,cntI);
  k_scan<<<1,1024,0,stream>>>(cntI,rptr,pos);
  k_scatter<<<(N_EDGESC+255)/256,256,0,stream>>>(dstp,pos,eidx);
  k_csr_edges<<<(N_EDGESC+255)/256,256,0,stream>>>(eidx,srcp,eattr,srcE,eattrC);
  k_loop_attr<<<(N_NODESC+3)/4,256,0,stream>>>(eattrC,rptr,cntI,lattr);
  k_conv_x<<<(N_NODESC*64+255)/256,256,0,stream>>>(x,Axhi,Axlo);
  k_ve3<<<1,256,0,stream>>>(We[0],aedge[0],We[1],aedge[1],We[2],aedge[2],ve3);
  {
    int tot=WB2+HC*HC;
    k_conv_w3<<<(tot+255)/256,256,0,stream>>>(W[0],W[1],W[2],Bthi3,Btlo3);
  }
  {
    const int NEDGET=N_EDGESC+N_NODESC*5;
    k_edge_terms3<<<(3*NEDGET+255)/256,256,0,stream>>>(eattrC,lattr,ve3,aeC3,ael3);
  }

  const int NBLK=5*((N_NODESC+127)/128);
  const int WBo[3]={WB0,WB1,WB2};
  for(int L=0;L<3;L++){
    int KP = (L==0)? 64 : HC;
    if(L==0)
      k_gemm_fused<3><<<NBLK,256,0,stream>>>(Axhi,Axlo,Bthi3+WBo[L],Btlo3+WBo[L],asrc[L],adst[L],hb,al,ar,N_NODESC,KP,NBLK);
    else
      k_gemm_fused<1><<<NBLK,256,0,stream>>>(Ahi,(const u16*)nullptr,Bthi3+WBo[L],(const u16*)nullptr,asrc[L],adst[L],hb,al,ar,N_NODESC,KP,NBLK);
    const float* aeL = aeC3 + (size_t)L*N_EDGESC*5;
    const float* aelL= ael3 + (size_t)L*N_NODESC*5;
    if(L<2)
      k_agg<true ,true ,false><<<(N_NODESC+3)/4,256,0,stream>>>(hb,srcE,rptr,cntI,al,ar,aelL,aeL,bias[L],Ahi,Wlin,pnode);
    else
      k_agg<false,false,true ><<<(N_NODESC+3)/4,256,0,stream>>>(hb,srcE,rptr,cntI,al,ar,aelL,aeL,bias[L],Ahi,Wlin,pnode);
  }
  k_graphout<<<(NGRAPH+3)/4,256,0,stream>>>(pnode,batch,blin,out);
}

// Round 14
// 466.309 us; speedup vs baseline: 1.3052x; 1.1348x over previous
//
#include <hip/hip_runtime.h>

#define N_NODESC 20000
#define N_EDGESC 320000
#define HC 640
#define NGRAPH 500

typedef unsigned short u16;
typedef unsigned int u32;
typedef __attribute__((ext_vector_type(8))) short bf16x8;
typedef __attribute__((ext_vector_type(4))) float f32x4;

__device__ __forceinline__ float wred_sum(float v){
  #pragma unroll
  for(int o=32;o;o>>=1) v += __shfl_xor(v,o,64);
  return v;
}
__device__ __forceinline__ float lrelu(float x){ return x>0.f? x:0.2f*x; }

__device__ __forceinline__ u16 f2bf(float f){
  u32 u=__float_as_uint(f);
  u32 r=u+0x7FFFu+((u>>16)&1u);
  return (u16)(r>>16);
}
__device__ __forceinline__ float bf2f(u16 s){ return __uint_as_float(((u32)s)<<16); }
__device__ __forceinline__ float bflo(u32 w){ return __uint_as_float(w<<16); }
__device__ __forceinline__ float bfhi(u32 w){ return __uint_as_float(w&0xFFFF0000u); }

__device__ __forceinline__ void gload16(const void* g, void* l){
  __builtin_amdgcn_global_load_lds((const __attribute__((address_space(1))) void*)g,
                                   (__attribute__((address_space(3))) void*)l, 16, 0, 0);
}

// ---------------- graph preprocessing (layer-invariant) ----------------

__global__ void k_count(const int* __restrict__ dst, int* __restrict__ cnt){
  int i=blockIdx.x*blockDim.x+threadIdx.x;
  if(i>=N_EDGESC) return;
  atomicAdd(&cnt[dst[i]],1);
}

__global__ void k_scan(const int* __restrict__ cnt, int* __restrict__ rptr, int* __restrict__ pos){
  __shared__ int ps[1024];
  int t=threadIdx.x;
  const int CH=20;
  int beg=t*CH, end=min(beg+CH, N_NODESC);
  int s=0;
  for(int i=beg;i<end;i++) s+=cnt[i];
  ps[t]=s; __syncthreads();
  for(int off=1;off<1024;off<<=1){
    int v=(t>=off)? ps[t-off]:0;
    __syncthreads();
    ps[t]+=v;
    __syncthreads();
  }
  int base=ps[t]-s;
  for(int i=beg;i<end;i++){ rptr[i]=base; pos[i]=base; base+=cnt[i]; }
}

__global__ void k_scatter(const int* __restrict__ dst, int* __restrict__ pos, int* __restrict__ eidx){
  int i=blockIdx.x*blockDim.x+threadIdx.x;
  if(i>=N_EDGESC) return;
  int j=atomicAdd(&pos[dst[i]],1);
  eidx[j]=i;
}

// resolve CSR permutation ONCE: srcE[j]=src[eidx[j]], eattrC[j]=eattr[eidx[j]]
__global__ void k_csr_edges(const int* __restrict__ eidx, const int* __restrict__ src,
                            const float* __restrict__ eattr,
                            int* __restrict__ srcE, float* __restrict__ eattrC){
  int j=blockIdx.x*blockDim.x+threadIdx.x;
  if(j>=N_EDGESC) return;
  int e=eidx[j];
  srcE[j]=src[e];
  const float* ep=&eattr[(size_t)e*10];
  float* op=&eattrC[(size_t)j*10];
  #pragma unroll
  for(int k=0;k<10;k++) op[k]=ep[k];
}

// scatter-mean of edge_attr per dst node via CSR (linear reads); one wave per node
__global__ __launch_bounds__(256) void k_loop_attr(const float* __restrict__ eattrC,
    const int* __restrict__ rptr, const int* __restrict__ cnt,
    float* __restrict__ lattr){
  int tid=threadIdx.x, lane=tid&63;
  int n=blockIdx.x*4+(tid>>6);
  if(n>=N_NODESC) return;
  int beg=rptr[n], deg=cnt[n];
  float s[10]={0,0,0,0,0,0,0,0,0,0};
  for(int off=lane; off<deg; off+=64){
    const float* ep=&eattrC[(size_t)(beg+off)*10];
    #pragma unroll
    for(int k=0;k<10;k++) s[k]+=ep[k];
  }
  float inv=1.f/fmaxf((float)deg,1.f);
  #pragma unroll
  for(int k=0;k<10;k++){
    float tot=wred_sum(s[k]);
    if(lane==0) lattr[(size_t)n*10+k]=tot*inv;
  }
}

// ---------------- conversions ----------------

__global__ void k_conv_x(const float* __restrict__ x, u16* __restrict__ hi, u16* __restrict__ lo){
  int idx=blockIdx.x*blockDim.x+threadIdx.x;
  if(idx>=N_NODESC*64) return;
  int n=idx>>6, kk=idx&63;
  float v = kk<43 ? x[n*43+kk] : 0.f;
  u16 h=f2bf(v);
  hi[idx]=h; lo[idx]=f2bf(v-bf2f(h));
}

// all 3 layers' transposed weights in one launch.
__global__ void k_conv_w3(const float* __restrict__ W0, const float* __restrict__ W1,
                          const float* __restrict__ W2,
                          u16* __restrict__ hi, u16* __restrict__ lo){
  const int R0=HC*64, R1=R0+HC*HC;
  const int TOT=R1+HC*HC;
  int idx=blockIdx.x*blockDim.x+threadIdx.x;
  if(idx>=TOT) return;
  const float* W; int local, KP, KL, base;
  if(idx<R0){ W=W0; local=idx; KP=64; KL=43; base=0; }
  else if(idx<R1){ W=W1; local=idx-R0; KP=HC; KL=HC; base=R0; }
  else { W=W2; local=idx-R1; KP=HC; KL=HC; base=R1; }
  int n=local/KP, kk=local-n*KP;
  float v = kk<KL ? W[(size_t)kk*HC+n] : 0.f;
  u16 h=f2bf(v);
  hi[base+local]=h;
  lo[base+local]=f2bf(v-bf2f(h));
}

// ---------------- attention-term kernels (all hoisted) ----------------

__global__ void k_ve3(const float* __restrict__ We0, const float* __restrict__ ae0,
                      const float* __restrict__ We1, const float* __restrict__ ae1,
                      const float* __restrict__ We2, const float* __restrict__ ae2,
                      float* __restrict__ ve3){
  int t=threadIdx.x;
  if(t>=150) return;
  int L=t/50, r=t-50*L, k=r/5, h=r%5;
  const float* We = (L==0)?We0:(L==1)?We1:We2;
  const float* ae = (L==0)?ae0:(L==1)?ae1:ae2;
  float s=0.f;
  for(int c=0;c<128;c++) s += We[k*HC + h*128 + c]*ae[h*128+c];
  ve3[t]=s;
}

// Cb = dot(bias2, wlin)  (scalar for the fused last-layer pool)
__global__ void k_cb(const float* __restrict__ bias, const float* __restrict__ wlin,
                     float* __restrict__ cb){
  int lane=threadIdx.x;
  float s=0.f;
  for(int c=lane;c<HC;c+=64) s+=bias[c]*wlin[c];
  s=wred_sum(s);
  if(lane==0) cb[0]=s;
}

// all 3 layers: aeC3[L][j][h] for r<E ; ael3[L][n][h] for r>=E
__global__ __launch_bounds__(256) void k_edge_terms3(const float* __restrict__ eattrC,
    const float* __restrict__ lattr, const float* __restrict__ ve3,
    float* __restrict__ aeC3, float* __restrict__ ael3){
  __shared__ float ves[150];
  if(threadIdx.x<150) ves[threadIdx.x]=ve3[threadIdx.x];
  __syncthreads();
  const int NEDGET=N_EDGESC+N_NODESC*5;
  int idx=blockIdx.x*blockDim.x+threadIdx.x;
  if(idx>=3*NEDGET) return;
  int L=idx/NEDGET, r=idx-L*NEDGET;
  const float* vl=&ves[L*50];
  if(r<N_EDGESC){
    float ev[10];
    const float* ep=&eattrC[(size_t)r*10];
    #pragma unroll
    for(int k=0;k<10;k++) ev[k]=ep[k];
    #pragma unroll
    for(int hh=0;hh<5;hh++){
      float s=0.f;
      #pragma unroll
      for(int k=0;k<10;k++) s+=ev[k]*vl[k*5+hh];
      aeC3[(size_t)L*N_EDGESC*5 + (size_t)r*5+hh]=s;
    }
  }else{
    int t=r-N_EDGESC;
    int n=t/5, h=t-5*n;
    float s=0.f;
    #pragma unroll
    for(int k=0;k<10;k++) s+=lattr[(size_t)n*10+k]*vl[k*5+h];
    ael3[(size_t)L*N_NODESC*5 + t]=s;
  }
}

// ---------------- GEMM + nodeatt ----------------

// NT=3: C=Ahi@Bhi+Alo@Bhi+Ahi@Blo (layer 0, tiny K). NT=1: C=A@Bhi (pure bf16).
// HB: write permuted bf16 hb. QOUT: per-head wlin dot q[n][5] (last layer).
// BK=32, double-buffered LDS. NT=1: 32 KiB -> 5 blocks/CU.
template<int NT, bool HB, bool QOUT>
__global__ __launch_bounds__(256,(NT==1)?5:3) void k_gemm_fused(
    const u16* __restrict__ Ahi, const u16* __restrict__ Alo,
    const u16* __restrict__ Bhi, const u16* __restrict__ Blo,
    const float* __restrict__ asrc, const float* __restrict__ adst,
    const float* __restrict__ wlin,
    u16* __restrict__ hb, float* __restrict__ al, float* __restrict__ ar,
    float* __restrict__ qn,
    int M, int KP, int nblk){
  constexpr int TERMS=(NT==3)?4:2;
  constexpr int BOFF =(NT==3)?8192:4096;
  __shared__ u16 lds[2*TERMS*4096];
  int tid=threadIdx.x;
  int lane=tid&63;
  int w=tid>>6;
  int l15=lane&15, lg=lane>>4;
  int orig=blockIdx.x;
  int q=nblk>>3, r=nblk&7;
  int xcd=orig&7, off=orig>>3;
  int wg=(xcd<r? xcd*(q+1) : r*(q+1)+(xcd-r)*q)+off;
  int by=wg/5, bx=wg-5*by;
  int row0=by*128, col0=bx*128;
  int wr=w>>1, wc=w&1;

  f32x4 zero = {0.f,0.f,0.f,0.f};
  f32x4 acc[4][4];
  #pragma unroll
  for(int i=0;i<4;i++)
    #pragma unroll
    for(int j=0;j<4;j++) acc[i][j]=zero;

  auto stage=[&](int b, int k0){
    u16* base = lds + b*TERMS*4096;
    #pragma unroll
    for(int c=0;c<2;c++){
      int sb=w+4*c;
      int col=k0+lg*8;
      size_t aoff=(size_t)(row0+sb*16+l15)*KP + col;
      size_t boff=(size_t)(col0+sb*16+l15)*KP + col;
      gload16(Ahi+aoff, base + sb*512);
      if constexpr(NT==3) gload16(Alo+aoff, base+4096 + sb*512);
      gload16(Bhi+boff, base+BOFF + sb*512);
      if constexpr(NT==3) gload16(Blo+boff, base+BOFF+4096 + sb*512);
    }
  };

  int nt=KP/32;
  stage(0,0);
  __syncthreads();
  int cur=0;
  for(int t=0;t<nt;t++){
    if(t+1<nt) stage(cur^1,(t+1)*32);
    u16* cb = lds + cur*TERMS*4096;
    bf16x8 ah[4], bh[4];
    #pragma unroll
    for(int i=0;i<4;i++){
      ah[i]=*(const bf16x8*)&cb[(wr*4+i)*512 + lane*8];
      bh[i]=*(const bf16x8*)&cb[BOFF+(wc*4+i)*512 + lane*8];
    }
    if constexpr(NT==3){
      bf16x8 alv[4], bl[4];
      #pragma unroll
      for(int i=0;i<4;i++){
        alv[i]=*(const bf16x8*)&cb[4096+(wr*4+i)*512+lane*8];
        bl[i] =*(const bf16x8*)&cb[BOFF+4096+(wc*4+i)*512+lane*8];
      }
      #pragma unroll
      for(int i=0;i<4;i++)
        #pragma unroll
        for(int j=0;j<4;j++){
          acc[i][j]=__builtin_amdgcn_mfma_f32_16x16x32_bf16(ah[i], bh[j],acc[i][j],0,0,0);
          acc[i][j]=__builtin_amdgcn_mfma_f32_16x16x32_bf16(alv[i],bh[j],acc[i][j],0,0,0);
          acc[i][j]=__builtin_amdgcn_mfma_f32_16x16x32_bf16(ah[i], bl[j],acc[i][j],0,0,0);
        }
    }else{
      #pragma unroll
      for(int i=0;i<4;i++)
        #pragma unroll
        for(int j=0;j<4;j++)
          acc[i][j]=__builtin_amdgcn_mfma_f32_16x16x32_bf16(ah[i],bh[j],acc[i][j],0,0,0);
    }
    __syncthreads();
    cur^=1;
  }

  // ---- epilogue: optional hb (permuted bf16), al/ar (+q) for head bx ----
  float asv[4], adv[4], wlv[4];
  #pragma unroll
  for(int j=0;j<4;j++){
    int c=col0+wc*64+j*16+l15;
    asv[j]=asrc[c]; adv[j]=adst[c];
    if(QOUT) wlv[j]=wlin[c];
  }
  if(HB){
    #pragma unroll
    for(int i=0;i<4;i++){
      #pragma unroll
      for(int j=0;j<4;j++){
        #pragma unroll
        for(int rr=0;rr<4;rr++){
          int row=row0+wr*64+i*16+lg*4+rr;
          if(row<M) hb[(size_t)row*HC + (j*16+l15)*10 + bx*2+wc]=f2bf(acc[i][j][rr]);
        }
      }
    }
  }
  float* redAl=(float*)lds;        // 256 floats
  float* redAr=redAl+256;
  float* redQ =redAr+256;
  #pragma unroll
  for(int i=0;i<4;i++){
    #pragma unroll
    for(int rr=0;rr<4;rr++){
      float sa=0.f, sd=0.f, sq=0.f;
      #pragma unroll
      for(int j=0;j<4;j++){
        sa+=acc[i][j][rr]*asv[j];
        sd+=acc[i][j][rr]*adv[j];
        if(QOUT) sq+=acc[i][j][rr]*wlv[j];
      }
      #pragma unroll
      for(int o=1;o<16;o<<=1){
        sa+=__shfl_xor(sa,o,64); sd+=__shfl_xor(sd,o,64);
        if(QOUT) sq+=__shfl_xor(sq,o,64);
      }
      if(l15==0){
        int lr=wr*64+i*16+lg*4+rr;
        redAl[lr*2+wc]=sa; redAr[lr*2+wc]=sd;
        if(QOUT) redQ[lr*2+wc]=sq;
      }
    }
  }
  __syncthreads();
  if(tid<128){
    int row=row0+tid;
    if(row<M){
      al[(size_t)row*5+bx]=redAl[tid*2]+redAl[tid*2+1];
      ar[(size_t)row*5+bx]=redAr[tid*2]+redAr[tid*2+1];
      if(QOUT) qn[(size_t)row*5+bx]=redQ[tid*2]+redQ[tid*2+1];
    }
  }
}

// fused segment-softmax + aggregation (layers 0/1); one wave per node.
// Direct-exp softmax; linear CSR edge data; 8-deep unrolled hb row gather.
// Always ReLU + bf16 output (next GEMM A). Single instantiation.
__global__ __launch_bounds__(256) void k_agg(const u16* __restrict__ hb, const int* __restrict__ srcE,
    const int* __restrict__ rptr, const int* __restrict__ cnt,
    const float* __restrict__ al, const float* __restrict__ ar, const float* __restrict__ ael,
    const float* __restrict__ aeC, const float* __restrict__ bias,
    u16* __restrict__ ohi){
  int tid=threadIdx.x, lane=tid&63;
  int n=blockIdx.x*4+(tid>>6);
  if(n>=N_NODESC) return;
  float arn[5], den[5], acc[10];
  #pragma unroll
  for(int hh=0;hh<5;hh++) arn[hh]=ar[n*5+hh];
  float p0[5];
  #pragma unroll
  for(int hh=0;hh<5;hh++){
    p0[hh]=__expf(lrelu(al[n*5+hh]+arn[hh]+ael[n*5+hh]));   // self-loop weight
    den[hh]=p0[hh];
  }
  {
    const u32* sp=(const u32*)(hb+(size_t)n*HC+lane*10);
    #pragma unroll
    for(int j2=0;j2<5;j2++){
      u32 wv=sp[j2];
      acc[2*j2]  =p0[j2]*bflo(wv);
      acc[2*j2+1]=p0[j2]*bfhi(wv);
    }
  }
  int beg=rptr[n], deg=cnt[n];
  for(int off0=0; off0<deg; off0+=64){
    int c=min(64,deg-off0);
    bool valid = lane<c;
    int s=0; float p[5];
    #pragma unroll
    for(int hh=0;hh<5;hh++) p[hh]=0.f;
    if(valid){
      int j=beg+off0+lane;
      s=srcE[j];
      const float* av=&aeC[(size_t)j*5];
      #pragma unroll
      for(int hh=0;hh<5;hh++) p[hh]=__expf(lrelu(al[s*5+hh]+arn[hh]+av[hh]));
    }
    #pragma unroll
    for(int hh=0;hh<5;hh++) den[hh]+=wred_sum(p[hh]);
    int j=0;
    for(; j+7<c; j+=8){
      int sjv[8];
      #pragma unroll
      for(int u=0;u<8;u++) sjv[u]=__shfl(s,j+u,64);
      u32 wv[8][5];
      #pragma unroll
      for(int u=0;u<8;u++){
        const u32* hr=(const u32*)(hb+(size_t)sjv[u]*HC+lane*10);
        #pragma unroll
        for(int j2=0;j2<5;j2++) wv[u][j2]=hr[j2];
      }
      #pragma unroll
      for(int u=0;u<8;u++){
        float pj[5];
        #pragma unroll
        for(int hh=0;hh<5;hh++) pj[hh]=__shfl(p[hh],j+u,64);
        #pragma unroll
        for(int j2=0;j2<5;j2++){
          acc[2*j2]  +=pj[j2]*bflo(wv[u][j2]);
          acc[2*j2+1]+=pj[j2]*bfhi(wv[u][j2]);
        }
      }
    }
    for(; j<c; j++){
      int sj=__shfl(s,j,64);
      float pj[5];
      #pragma unroll
      for(int hh=0;hh<5;hh++) pj[hh]=__shfl(p[hh],j,64);
      const u32* hr=(const u32*)(hb+(size_t)sj*HC+lane*10);
      #pragma unroll
      for(int j2=0;j2<5;j2++){
        u32 wv=hr[j2];
        acc[2*j2]  +=pj[j2]*bflo(wv);
        acc[2*j2+1]+=pj[j2]*bfhi(wv);
      }
    }
  }
  #pragma unroll
  for(int k=0;k<10;k++){
    int ccol=lane+64*k;
    float vv=acc[k]/(den[k>>1]+1e-16f)+bias[ccol];
    vv=fmaxf(vv,0.f);
    ohi[(size_t)n*HC+ccol]=f2bf(vv);
  }
}

// last-layer agg fused with pooling dot: per node, only 5 scalars per edge.
// 16 lanes per node (4 nodes per wave). q is 400KB -> L2-resident.
__global__ __launch_bounds__(256) void k_agg_last(const float* __restrict__ qn,
    const int* __restrict__ srcE, const int* __restrict__ rptr, const int* __restrict__ cnt,
    const float* __restrict__ al, const float* __restrict__ ar, const float* __restrict__ ael,
    const float* __restrict__ aeC, const float* __restrict__ cb,
    float* __restrict__ pnode){
  int tid=threadIdx.x;
  int sub=tid&15;
  int n=blockIdx.x*16+(tid>>4);
  if(n>=N_NODESC) return;
  float arn[5], den[5], qs[5];
  #pragma unroll
  for(int h=0;h<5;h++) arn[h]=ar[n*5+h];
  #pragma unroll
  for(int h=0;h<5;h++){ den[h]=0.f; qs[h]=0.f; }
  if(sub==0){
    #pragma unroll
    for(int h=0;h<5;h++){
      float pp=__expf(lrelu(al[n*5+h]+arn[h]+ael[n*5+h]));
      den[h]=pp; qs[h]=pp*qn[(size_t)n*5+h];
    }
  }
  int beg=rptr[n], deg=cnt[n];
  for(int off=sub; off<deg; off+=16){
    int j=beg+off;
    int s=srcE[j];
    const float* av=&aeC[(size_t)j*5];
    const float* qv=&qn[(size_t)s*5];
    #pragma unroll
    for(int h=0;h<5;h++){
      float pp=__expf(lrelu(al[s*5+h]+arn[h]+av[h]));
      den[h]+=pp; qs[h]+=pp*qv[h];
    }
  }
  #pragma unroll
  for(int h=0;h<5;h++){
    #pragma unroll
    for(int o=1;o<16;o<<=1){
      den[h]+=__shfl_xor(den[h],o,16);
      qs[h]+=__shfl_xor(qs[h],o,16);
    }
  }
  if(sub==0){
    float s=0.f;
    #pragma unroll
    for(int h=0;h<5;h++) s+=qs[h]/(den[h]+1e-16f);
    pnode[n]=s+cb[0];
  }
}

// per-graph mean over sorted batch segments (binary search, no atomics)
__global__ __launch_bounds__(256) void k_graphout(const float* __restrict__ pnode,
    const int* __restrict__ batch, const float* __restrict__ blin,
    float* __restrict__ out){
  int tid=threadIdx.x, lane=tid&63;
  int g=blockIdx.x*4+(tid>>6);
  if(g>=NGRAPH) return;
  auto lb=[&](int val){
    int lo=0, hi=N_NODESC;
    while(lo<hi){ int mid=(lo+hi)>>1; if(batch[mid]<val) lo=mid+1; else hi=mid; }
    return lo;
  };
  int s0=lb(g), s1=lb(g+1);
  float s=0.f;
  for(int i=s0+lane;i<s1;i+=64) s+=pnode[i];
  s=wred_sum(s);
  if(lane==0) out[g]=s/fmaxf((float)(s1-s0),1.f)+blin[0];
}

// ---------------- launch ----------------

extern "C" void kernel_launch(void* const* d_in, const int* in_sizes, int n_in,
                              void* d_out, int out_size, void* d_ws, size_t ws_size,
                              hipStream_t stream){
  const float* x     = (const float*)d_in[0];
  const float* eattr = (const float*)d_in[1];
  const float* W[3]    ={(const float*)d_in[2],(const float*)d_in[8],(const float*)d_in[14]};
  const float* We[3]   ={(const float*)d_in[3],(const float*)d_in[9],(const float*)d_in[15]};
  const float* asrc[3] ={(const float*)d_in[4],(const float*)d_in[10],(const float*)d_in[16]};
  const float* adst[3] ={(const float*)d_in[5],(const float*)d_in[11],(const float*)d_in[17]};
  const float* aedge[3]={(const float*)d_in[6],(const float*)d_in[12],(const float*)d_in[18]};
  const float* bias[3] ={(const float*)d_in[7],(const float*)d_in[13],(const float*)d_in[19]};
  const float* Wlin  = (const float*)d_in[20];
  const float* blin  = (const float*)d_in[21];
  const int* eind    = (const int*)d_in[22];
  const int* srcp    = eind;
  const int* dstp    = eind + N_EDGESC;
  const int* batch   = (const int*)d_in[23];
  float* out = (float*)d_out;

  char* ws=(char*)d_ws;
  size_t o=0;
  auto alloc=[&](size_t bytes)->void*{ void* p=ws+o; o=(o+bytes+255)&~(size_t)255; return p; };
  u16* hb   =(u16*)alloc((size_t)N_NODESC*HC*2);           // permuted bf16 h
  u16* Ahi =(u16*)alloc((size_t)N_NODESC*HC*2);            // agg bf16 out (next GEMM A)
  u16* Axhi=(u16*)alloc((size_t)N_NODESC*64*2);            // converted x (KP=64)
  u16* Axlo=(u16*)alloc((size_t)N_NODESC*64*2);
  const int WB0=0, WB1=HC*64, WB2=WB1+HC*HC;               // packed Bt offsets
  u16* Bthi3=(u16*)alloc((size_t)(WB2+HC*HC)*2);
  u16* Btlo3=(u16*)alloc((size_t)(WB2+HC*HC)*2);
  float* al   =(float*)alloc((size_t)N_NODESC*5*4);
  float* ar   =(float*)alloc((size_t)N_NODESC*5*4);
  float* qn   =(float*)alloc((size_t)N_NODESC*5*4);
  float* ael3 =(float*)alloc((size_t)3*N_NODESC*5*4);
  float* aeC3 =(float*)alloc((size_t)3*N_EDGESC*5*4);
  float* lattr=(float*)alloc((size_t)N_NODESC*10*4);
  float* eattrC=(float*)alloc((size_t)N_EDGESC*10*4);
  float* ve3  =(float*)alloc(256*4);
  float* cbv  =(float*)alloc(64*4);
  float* pnode=(float*)alloc((size_t)N_NODESC*4);
  int* cntI   =(int*)alloc((size_t)N_NODESC*4);
  int* rptr   =(int*)alloc((size_t)N_NODESC*4);
  int* pos    =(int*)alloc((size_t)N_NODESC*4);
  int* eidx   =(int*)alloc((size_t)N_EDGESC*4);
  int* srcE   =(int*)alloc((size_t)N_EDGESC*4);

  hipMemsetAsync(cntI,0,(size_t)N_NODESC*4,stream);

  k_count<<<(N_EDGESC+255)/256,256,0,stream>>>(dstp,cntI);
  k_scan<<<1,1024,0,stream>>>(cntI,rptr,pos);
  k_scatter<<<(N_EDGESC+255)/256,256,0,stream>>>(dstp,pos,eidx);
  k_csr_edges<<<(N_EDGESC+255)/256,256,0,stream>>>(eidx,srcp,eattr,srcE,eattrC);
  k_loop_attr<<<(N_NODESC+3)/4,256,0,stream>>>(eattrC,rptr,cntI,lattr);
  k_conv_x<<<(N_NODESC*64+255)/256,256,0,stream>>>(x,Axhi,Axlo);
  k_ve3<<<1,256,0,stream>>>(We[0],aedge[0],We[1],aedge[1],We[2],aedge[2],ve3);
  k_cb<<<1,64,0,stream>>>(bias[2],Wlin,cbv);
  {
    int tot=WB2+HC*HC;
    k_conv_w3<<<(tot+255)/256,256,0,stream>>>(W[0],W[1],W[2],Bthi3,Btlo3);
  }
  {
    const int NEDGET=N_EDGESC+N_NODESC*5;
    k_edge_terms3<<<(3*NEDGET+255)/256,256,0,stream>>>(eattrC,lattr,ve3,aeC3,ael3);
  }

  const int NBLK=5*((N_NODESC+127)/128);
  const int WBo[3]={WB0,WB1,WB2};
  for(int L=0;L<3;L++){
    int KP = (L==0)? 64 : HC;
    const float* aeL = aeC3 + (size_t)L*N_EDGESC*5;
    const float* aelL= ael3 + (size_t)L*N_NODESC*5;
    if(L==0){
      k_gemm_fused<3,true,false><<<NBLK,256,0,stream>>>(Axhi,Axlo,Bthi3+WBo[L],Btlo3+WBo[L],
          asrc[L],adst[L],Wlin,hb,al,ar,qn,N_NODESC,KP,NBLK);
      k_agg<<<(N_NODESC+3)/4,256,0,stream>>>(hb,srcE,rptr,cntI,al,ar,aelL,aeL,bias[L],Ahi);
    }else if(L==1){
      k_gemm_fused<1,true,false><<<NBLK,256,0,stream>>>(Ahi,(const u16*)nullptr,Bthi3+WBo[L],(const u16*)nullptr,
          asrc[L],adst[L],Wlin,hb,al,ar,qn,N_NODESC,KP,NBLK);
      k_agg<<<(N_NODESC+3)/4,256,0,stream>>>(hb,srcE,rptr,cntI,al,ar,aelL,aeL,bias[L],Ahi);
    }else{
      k_gemm_fused<1,false,true><<<NBLK,256,0,stream>>>(Ahi,(const u16*)nullptr,Bthi3+WBo[L],(const u16*)nullptr,
          asrc[L],adst[L],Wlin,hb,al,ar,qn,N_NODESC,KP,NBLK);
      k_agg_last<<<(N_NODESC+15)/16,256,0,stream>>>(qn,srcE,rptr,cntI,al,ar,aelL,aeL,cbv,pnode);
    }
  }
  k_graphout<<<(NGRAPH+3)/4,256,0,stream>>>(pnode,batch,blin,out);
}

// Round 15
// 442.962 us; speedup vs baseline: 1.3740x; 1.0527x over previous
//
#include <hip/hip_runtime.h>

#define N_NODESC 20000
#define N_EDGESC 320000
#define HC 640
#define NGRAPH 500

typedef unsigned short u16;
typedef unsigned int u32;
typedef __attribute__((ext_vector_type(8))) short bf16x8;
typedef __attribute__((ext_vector_type(4))) float f32x4;

__device__ __forceinline__ float wred_sum(float v){
  #pragma unroll
  for(int o=32;o;o>>=1) v += __shfl_xor(v,o,64);
  return v;
}
__device__ __forceinline__ float lrelu(float x){ return x>0.f? x:0.2f*x; }

__device__ __forceinline__ u16 f2bf(float f){
  u32 u=__float_as_uint(f);
  u32 r=u+0x7FFFu+((u>>16)&1u);
  return (u16)(r>>16);
}
__device__ __forceinline__ float bf2f(u16 s){ return __uint_as_float(((u32)s)<<16); }
__device__ __forceinline__ float bflo(u32 w){ return __uint_as_float(w<<16); }
__device__ __forceinline__ float bfhi(u32 w){ return __uint_as_float(w&0xFFFF0000u); }

__device__ __forceinline__ void gload16(const void* g, void* l){
  __builtin_amdgcn_global_load_lds((const __attribute__((address_space(1))) void*)g,
                                   (__attribute__((address_space(3))) void*)l, 16, 0, 0);
}

// ---------------- graph preprocessing (layer-invariant) ----------------

__global__ void k_count(const int* __restrict__ dst, int* __restrict__ cnt){
  int i=blockIdx.x*blockDim.x+threadIdx.x;
  if(i>=N_EDGESC) return;
  atomicAdd(&cnt[dst[i]],1);
}

__global__ void k_scan(const int* __restrict__ cnt, int* __restrict__ rptr, int* __restrict__ pos){
  __shared__ int ps[1024];
  int t=threadIdx.x;
  const int CH=20;
  int beg=t*CH, end=min(beg+CH, N_NODESC);
  int s=0;
  for(int i=beg;i<end;i++) s+=cnt[i];
  ps[t]=s; __syncthreads();
  for(int off=1;off<1024;off<<=1){
    int v=(t>=off)? ps[t-off]:0;
    __syncthreads();
    ps[t]+=v;
    __syncthreads();
  }
  int base=ps[t]-s;
  for(int i=beg;i<end;i++){ rptr[i]=base; pos[i]=base; base+=cnt[i]; }
}

__global__ void k_scatter(const int* __restrict__ dst, int* __restrict__ pos,
                          int* __restrict__ eidx, int* __restrict__ dstC){
  int i=blockIdx.x*blockDim.x+threadIdx.x;
  if(i>=N_EDGESC) return;
  int d=dst[i];
  int j=atomicAdd(&pos[d],1);
  eidx[j]=i;
  dstC[j]=d;
}

// resolve CSR permutation ONCE: srcE[j]=src[eidx[j]], eattrC[j]=eattr[eidx[j]]
__global__ void k_csr_edges(const int* __restrict__ eidx, const int* __restrict__ src,
                            const float* __restrict__ eattr,
                            int* __restrict__ srcE, float* __restrict__ eattrC){
  int j=blockIdx.x*blockDim.x+threadIdx.x;
  if(j>=N_EDGESC) return;
  int e=eidx[j];
  srcE[j]=src[e];
  const float* ep=&eattr[(size_t)e*10];
  float* op=&eattrC[(size_t)j*10];
  #pragma unroll
  for(int k=0;k<10;k++) op[k]=ep[k];
}

// scatter-mean of edge_attr per dst node via CSR (linear reads); one wave per node
__global__ __launch_bounds__(256) void k_loop_attr(const float* __restrict__ eattrC,
    const int* __restrict__ rptr, const int* __restrict__ cnt,
    float* __restrict__ lattr){
  int tid=threadIdx.x, lane=tid&63;
  int n=blockIdx.x*4+(tid>>6);
  if(n>=N_NODESC) return;
  int beg=rptr[n], deg=cnt[n];
  float s[10]={0,0,0,0,0,0,0,0,0,0};
  for(int off=lane; off<deg; off+=64){
    const float* ep=&eattrC[(size_t)(beg+off)*10];
    #pragma unroll
    for(int k=0;k<10;k++) s[k]+=ep[k];
  }
  float inv=1.f/fmaxf((float)deg,1.f);
  #pragma unroll
  for(int k=0;k<10;k++){
    float tot=wred_sum(s[k]);
    if(lane==0) lattr[(size_t)n*10+k]=tot*inv;
  }
}

// ---------------- conversions ----------------

__global__ void k_conv_x(const float* __restrict__ x, u16* __restrict__ hi, u16* __restrict__ lo){
  int idx=blockIdx.x*blockDim.x+threadIdx.x;
  if(idx>=N_NODESC*64) return;
  int n=idx>>6, kk=idx&63;
  float v = kk<43 ? x[n*43+kk] : 0.f;
  u16 h=f2bf(v);
  hi[idx]=h; lo[idx]=f2bf(v-bf2f(h));
}

// all 3 layers' transposed weights in one launch.
__global__ void k_conv_w3(const float* __restrict__ W0, const float* __restrict__ W1,
                          const float* __restrict__ W2,
                          u16* __restrict__ hi, u16* __restrict__ lo){
  const int R0=HC*64, R1=R0+HC*HC;
  const int TOT=R1+HC*HC;
  int idx=blockIdx.x*blockDim.x+threadIdx.x;
  if(idx>=TOT) return;
  const float* W; int local, KP, KL, base;
  if(idx<R0){ W=W0; local=idx; KP=64; KL=43; base=0; }
  else if(idx<R1){ W=W1; local=idx-R0; KP=HC; KL=HC; base=R0; }
  else { W=W2; local=idx-R1; KP=HC; KL=HC; base=R1; }
  int n=local/KP, kk=local-n*KP;
  float v = kk<KL ? W[(size_t)kk*HC+n] : 0.f;
  u16 h=f2bf(v);
  hi[base+local]=h;
  lo[base+local]=f2bf(v-bf2f(h));
}

// ---------------- attention-term kernels (all hoisted) ----------------

__global__ void k_ve3(const float* __restrict__ We0, const float* __restrict__ ae0,
                      const float* __restrict__ We1, const float* __restrict__ ae1,
                      const float* __restrict__ We2, const float* __restrict__ ae2,
                      float* __restrict__ ve3){
  int t=threadIdx.x;
  if(t>=150) return;
  int L=t/50, r=t-50*L, k=r/5, h=r%5;
  const float* We = (L==0)?We0:(L==1)?We1:We2;
  const float* ae = (L==0)?ae0:(L==1)?ae1:ae2;
  float s=0.f;
  for(int c=0;c<128;c++) s += We[k*HC + h*128 + c]*ae[h*128+c];
  ve3[t]=s;
}

// Cb = dot(bias2, wlin)  (scalar for the fused last-layer pool)
__global__ void k_cb(const float* __restrict__ bias, const float* __restrict__ wlin,
                     float* __restrict__ cb){
  int lane=threadIdx.x;
  float s=0.f;
  for(int c=lane;c<HC;c+=64) s+=bias[c]*wlin[c];
  s=wred_sum(s);
  if(lane==0) cb[0]=s;
}

// all 3 layers: aeC3[L][j][h] for r<E ; ael3[L][n][h] for r>=E
__global__ __launch_bounds__(256) void k_edge_terms3(const float* __restrict__ eattrC,
    const float* __restrict__ lattr, const float* __restrict__ ve3,
    float* __restrict__ aeC3, float* __restrict__ ael3){
  __shared__ float ves[150];
  if(threadIdx.x<150) ves[threadIdx.x]=ve3[threadIdx.x];
  __syncthreads();
  const int NEDGET=N_EDGESC+N_NODESC*5;
  int idx=blockIdx.x*blockDim.x+threadIdx.x;
  if(idx>=3*NEDGET) return;
  int L=idx/NEDGET, r=idx-L*NEDGET;
  const float* vl=&ves[L*50];
  if(r<N_EDGESC){
    float ev[10];
    const float* ep=&eattrC[(size_t)r*10];
    #pragma unroll
    for(int k=0;k<10;k++) ev[k]=ep[k];
    #pragma unroll
    for(int hh=0;hh<5;hh++){
      float s=0.f;
      #pragma unroll
      for(int k=0;k<10;k++) s+=ev[k]*vl[k*5+hh];
      aeC3[(size_t)L*N_EDGESC*5 + (size_t)r*5+hh]=s;
    }
  }else{
    int t=r-N_EDGESC;
    int n=t/5, h=t-5*n;
    float s=0.f;
    #pragma unroll
    for(int k=0;k<10;k++) s+=lattr[(size_t)n*10+k]*vl[k*5+h];
    ael3[(size_t)L*N_NODESC*5 + t]=s;
  }
}

// per-layer edge softmax weights (edge-parallel, full occupancy):
// wE[j][h] = exp(lrelu(al[src]+ar[dst]+aeC[j]))
__global__ void k_edgew(const int* __restrict__ srcE, const int* __restrict__ dstC,
                        const float* __restrict__ al, const float* __restrict__ ar,
                        const float* __restrict__ aeC, float* __restrict__ wE){
  int j=blockIdx.x*blockDim.x+threadIdx.x;
  if(j>=N_EDGESC) return;
  int s=srcE[j], d=dstC[j];
  const float* av=&aeC[(size_t)j*5];
  float* wp=&wE[(size_t)j*5];
  #pragma unroll
  for(int h=0;h<5;h++)
    wp[h]=__expf(lrelu(al[s*5+h]+ar[d*5+h]+av[h]));
}

// ---------------- GEMM + nodeatt ----------------

// NT=3: C=Ahi@Bhi+Alo@Bhi+Ahi@Blo (layer 0, tiny K). NT=1: C=A@Bhi (pure bf16).
// HB: write permuted bf16 hb. QOUT: per-head wlin dot q[n][5] (last layer).
// BK=32, double-buffered LDS. NT=1: 32 KiB -> 5 blocks/CU.
template<int NT, bool HB, bool QOUT>
__global__ __launch_bounds__(256,(NT==1)?5:3) void k_gemm_fused(
    const u16* __restrict__ Ahi, const u16* __restrict__ Alo,
    const u16* __restrict__ Bhi, const u16* __restrict__ Blo,
    const float* __restrict__ asrc, const float* __restrict__ adst,
    const float* __restrict__ wlin,
    u16* __restrict__ hb, float* __restrict__ al, float* __restrict__ ar,
    float* __restrict__ qn,
    int M, int KP, int nblk){
  constexpr int TERMS=(NT==3)?4:2;
  constexpr int BOFF =(NT==3)?8192:4096;
  __shared__ u16 lds[2*TERMS*4096];
  int tid=threadIdx.x;
  int lane=tid&63;
  int w=tid>>6;
  int l15=lane&15, lg=lane>>4;
  int orig=blockIdx.x;
  int q=nblk>>3, r=nblk&7;
  int xcd=orig&7, off=orig>>3;
  int wg=(xcd<r? xcd*(q+1) : r*(q+1)+(xcd-r)*q)+off;
  int by=wg/5, bx=wg-5*by;
  int row0=by*128, col0=bx*128;
  int wr=w>>1, wc=w&1;

  f32x4 zero = {0.f,0.f,0.f,0.f};
  f32x4 acc[4][4];
  #pragma unroll
  for(int i=0;i<4;i++)
    #pragma unroll
    for(int j=0;j<4;j++) acc[i][j]=zero;

  auto stage=[&](int b, int k0){
    u16* base = lds + b*TERMS*4096;
    #pragma unroll
    for(int c=0;c<2;c++){
      int sb=w+4*c;
      int col=k0+lg*8;
      size_t aoff=(size_t)(row0+sb*16+l15)*KP + col;
      size_t boff=(size_t)(col0+sb*16+l15)*KP + col;
      gload16(Ahi+aoff, base + sb*512);
      if constexpr(NT==3) gload16(Alo+aoff, base+4096 + sb*512);
      gload16(Bhi+boff, base+BOFF + sb*512);
      if constexpr(NT==3) gload16(Blo+boff, base+BOFF+4096 + sb*512);
    }
  };

  int nt=KP/32;
  stage(0,0);
  __syncthreads();
  int cur=0;
  for(int t=0;t<nt;t++){
    if(t+1<nt) stage(cur^1,(t+1)*32);
    u16* cb = lds + cur*TERMS*4096;
    bf16x8 ah[4], bh[4];
    #pragma unroll
    for(int i=0;i<4;i++){
      ah[i]=*(const bf16x8*)&cb[(wr*4+i)*512 + lane*8];
      bh[i]=*(const bf16x8*)&cb[BOFF+(wc*4+i)*512 + lane*8];
    }
    if constexpr(NT==3){
      bf16x8 alv[4], bl[4];
      #pragma unroll
      for(int i=0;i<4;i++){
        alv[i]=*(const bf16x8*)&cb[4096+(wr*4+i)*512+lane*8];
        bl[i] =*(const bf16x8*)&cb[BOFF+4096+(wc*4+i)*512+lane*8];
      }
      #pragma unroll
      for(int i=0;i<4;i++)
        #pragma unroll
        for(int j=0;j<4;j++){
          acc[i][j]=__builtin_amdgcn_mfma_f32_16x16x32_bf16(ah[i], bh[j],acc[i][j],0,0,0);
          acc[i][j]=__builtin_amdgcn_mfma_f32_16x16x32_bf16(alv[i],bh[j],acc[i][j],0,0,0);
          acc[i][j]=__builtin_amdgcn_mfma_f32_16x16x32_bf16(ah[i], bl[j],acc[i][j],0,0,0);
        }
    }else{
      #pragma unroll
      for(int i=0;i<4;i++)
        #pragma unroll
        for(int j=0;j<4;j++)
          acc[i][j]=__builtin_amdgcn_mfma_f32_16x16x32_bf16(ah[i],bh[j],acc[i][j],0,0,0);
    }
    __syncthreads();
    cur^=1;
  }

  // ---- epilogue: optional hb (permuted bf16), al/ar (+q) for head bx ----
  float asv[4], adv[4], wlv[4];
  #pragma unroll
  for(int j=0;j<4;j++){
    int c=col0+wc*64+j*16+l15;
    asv[j]=asrc[c]; adv[j]=adst[c];
    if(QOUT) wlv[j]=wlin[c];
  }
  if(HB){
    #pragma unroll
    for(int i=0;i<4;i++){
      #pragma unroll
      for(int j=0;j<4;j++){
        #pragma unroll
        for(int rr=0;rr<4;rr++){
          int row=row0+wr*64+i*16+lg*4+rr;
          if(row<M) hb[(size_t)row*HC + (j*16+l15)*10 + bx*2+wc]=f2bf(acc[i][j][rr]);
        }
      }
    }
  }
  float* redAl=(float*)lds;        // 256 floats
  float* redAr=redAl+256;
  float* redQ =redAr+256;
  #pragma unroll
  for(int i=0;i<4;i++){
    #pragma unroll
    for(int rr=0;rr<4;rr++){
      float sa=0.f, sd=0.f, sq=0.f;
      #pragma unroll
      for(int j=0;j<4;j++){
        sa+=acc[i][j][rr]*asv[j];
        sd+=acc[i][j][rr]*adv[j];
        if(QOUT) sq+=acc[i][j][rr]*wlv[j];
      }
      #pragma unroll
      for(int o=1;o<16;o<<=1){
        sa+=__shfl_xor(sa,o,64); sd+=__shfl_xor(sd,o,64);
        if(QOUT) sq+=__shfl_xor(sq,o,64);
      }
      if(l15==0){
        int lr=wr*64+i*16+lg*4+rr;
        redAl[lr*2+wc]=sa; redAr[lr*2+wc]=sd;
        if(QOUT) redQ[lr*2+wc]=sq;
      }
    }
  }
  __syncthreads();
  if(tid<128){
    int row=row0+tid;
    if(row<M){
      al[(size_t)row*5+bx]=redAl[tid*2]+redAl[tid*2+1];
      ar[(size_t)row*5+bx]=redAr[tid*2]+redAr[tid*2+1];
      if(QOUT) qn[(size_t)row*5+bx]=redQ[tid*2]+redQ[tid*2+1];
    }
  }
}

// aggregation (layers 0/1); one wave per node. Softmax weights precomputed
// (wE, edge-parallel) -> NO cross-lane shuffles, NO exp in hot loop; den
// accumulated redundantly per lane from broadcast wE loads. 4-deep gather.
__global__ __launch_bounds__(256) void k_agg(const u16* __restrict__ hb, const int* __restrict__ srcE,
    const int* __restrict__ rptr, const int* __restrict__ cnt,
    const float* __restrict__ al, const float* __restrict__ ar, const float* __restrict__ ael,
    const float* __restrict__ wE, const float* __restrict__ bias,
    u16* __restrict__ ohi){
  int tid=threadIdx.x, lane=tid&63;
  int n=blockIdx.x*4+(tid>>6);
  if(n>=N_NODESC) return;
  float den[5], acc[10];
  #pragma unroll
  for(int h=0;h<5;h++)
    den[h]=__expf(lrelu(al[n*5+h]+ar[n*5+h]+ael[n*5+h]));  // self-loop p0
  {
    const u32* sp=(const u32*)(hb+(size_t)n*HC+lane*10);
    #pragma unroll
    for(int j2=0;j2<5;j2++){
      u32 wv=sp[j2];
      acc[2*j2]  =den[j2]*bflo(wv);
      acc[2*j2+1]=den[j2]*bfhi(wv);
    }
  }
  int beg=rptr[n], end=beg+cnt[n];
  int j=beg;
  for(; j+3<end; j+=4){
    int sj[4];
    #pragma unroll
    for(int u=0;u<4;u++) sj[u]=srcE[j+u];
    float w[4][5];
    #pragma unroll
    for(int u=0;u<4;u++){
      const float* wp=&wE[(size_t)(j+u)*5];
      #pragma unroll
      for(int h=0;h<5;h++) w[u][h]=wp[h];
    }
    u32 wv[4][5];
    #pragma unroll
    for(int u=0;u<4;u++){
      const u32* hr=(const u32*)(hb+(size_t)sj[u]*HC+lane*10);
      #pragma unroll
      for(int j2=0;j2<5;j2++) wv[u][j2]=hr[j2];
    }
    #pragma unroll
    for(int u=0;u<4;u++){
      #pragma unroll
      for(int j2=0;j2<5;j2++){
        den[j2]+=w[u][j2]*0.2f;     // placeholder avoided; real add below
      }
    }
    // real den accumulation (undo placeholder): compute correctly instead
    #pragma unroll
    for(int u=0;u<4;u++){
      #pragma unroll
      for(int j2=0;j2<5;j2++){
        den[j2]-=w[u][j2]*0.2f;
        den[j2]+=w[u][j2];
      }
    }
    #pragma unroll
    for(int u=0;u<4;u++){
      #pragma unroll
      for(int j2=0;j2<5;j2++){
        acc[2*j2]  +=w[u][j2]*bflo(wv[u][j2]);
        acc[2*j2+1]+=w[u][j2]*bfhi(wv[u][j2]);
      }
    }
  }
  for(; j<end; j++){
    int sj=srcE[j];
    const float* wp=&wE[(size_t)j*5];
    float w[5];
    #pragma unroll
    for(int h=0;h<5;h++){ w[h]=wp[h]; den[h]+=w[h]; }
    const u32* hr=(const u32*)(hb+(size_t)sj*HC+lane*10);
    #pragma unroll
    for(int j2=0;j2<5;j2++){
      u32 wv=hr[j2];
      acc[2*j2]  +=w[j2]*bflo(wv);
      acc[2*j2+1]+=w[j2]*bfhi(wv);
    }
  }
  #pragma unroll
  for(int k=0;k<10;k++){
    int ccol=lane+64*k;
    float vv=acc[k]/(den[k>>1]+1e-16f)+bias[ccol];
    vv=fmaxf(vv,0.f);
    ohi[(size_t)n*HC+ccol]=f2bf(vv);
  }
}

// last-layer agg fused with pooling dot: per node, only 5 scalars per edge.
// 16 lanes per node (4 nodes per wave). q is 400KB -> L2-resident.
__global__ __launch_bounds__(256) void k_agg_last(const float* __restrict__ qn,
    const int* __restrict__ srcE, const int* __restrict__ rptr, const int* __restrict__ cnt,
    const float* __restrict__ al, const float* __restrict__ ar, const float* __restrict__ ael,
    const float* __restrict__ aeC, const float* __restrict__ cb,
    float* __restrict__ pnode){
  int tid=threadIdx.x;
  int sub=tid&15;
  int n=blockIdx.x*16+(tid>>4);
  if(n>=N_NODESC) return;
  float arn[5], den[5], qs[5];
  #pragma unroll
  for(int h=0;h<5;h++) arn[h]=ar[n*5+h];
  #pragma unroll
  for(int h=0;h<5;h++){ den[h]=0.f; qs[h]=0.f; }
  if(sub==0){
    #pragma unroll
    for(int h=0;h<5;h++){
      float pp=__expf(lrelu(al[n*5+h]+arn[h]+ael[n*5+h]));
      den[h]=pp; qs[h]=pp*qn[(size_t)n*5+h];
    }
  }
  int beg=rptr[n], deg=cnt[n];
  for(int off=sub; off<deg; off+=16){
    int j=beg+off;
    int s=srcE[j];
    const float* av=&aeC[(size_t)j*5];
    const float* qv=&qn[(size_t)s*5];
    #pragma unroll
    for(int h=0;h<5;h++){
      float pp=__expf(lrelu(al[s*5+h]+arn[h]+av[h]));
      den[h]+=pp; qs[h]+=pp*qv[h];
    }
  }
  #pragma unroll
  for(int h=0;h<5;h++){
    #pragma unroll
    for(int o=1;o<16;o<<=1){
      den[h]+=__shfl_xor(den[h],o,16);
      qs[h]+=__shfl_xor(qs[h],o,16);
    }
  }
  if(sub==0){
    float s=0.f;
    #pragma unroll
    for(int h=0;h<5;h++) s+=qs[h]/(den[h]+1e-16f);
    pnode[n]=s+cb[0];
  }
}

// per-graph mean over sorted batch segments (binary search, no atomics)
__global__ __launch_bounds__(256) void k_graphout(const float* __restrict__ pnode,
    const int* __restrict__ batch, const float* __restrict__ blin,
    float* __restrict__ out){
  int tid=threadIdx.x, lane=tid&63;
  int g=blockIdx.x*4+(tid>>6);
  if(g>=NGRAPH) return;
  auto lb=[&](int val){
    int lo=0, hi=N_NODESC;
    while(lo<hi){ int mid=(lo+hi)>>1; if(batch[mid]<val) lo=mid+1; else hi=mid; }
    return lo;
  };
  int s0=lb(g), s1=lb(g+1);
  float s=0.f;
  for(int i=s0+lane;i<s1;i+=64) s+=pnode[i];
  s=wred_sum(s);
  if(lane==0) out[g]=s/fmaxf((float)(s1-s0),1.f)+blin[0];
}

// ---------------- launch ----------------

extern "C" void kernel_launch(void* const* d_in, const int* in_sizes, int n_in,
                              void* d_out, int out_size, void* d_ws, size_t ws_size,
                              hipStream_t stream){
  const float* x     = (const float*)d_in[0];
  const float* eattr = (const float*)d_in[1];
  const float* W[3]    ={(const float*)d_in[2],(const float*)d_in[8],(const float*)d_in[14]};
  const float* We[3]   ={(const float*)d_in[3],(const float*)d_in[9],(const float*)d_in[15]};
  const float* asrc[3] ={(const float*)d_in[4],(const float*)d_in[10],(const float*)d_in[16]};
  const float* adst[3] ={(const float*)d_in[5],(const float*)d_in[11],(const float*)d_in[17]};
  const float* aedge[3]={(const float*)d_in[6],(const float*)d_in[12],(const float*)d_in[18]};
  const float* bias[3] ={(const float*)d_in[7],(const float*)d_in[13],(const float*)d_in[19]};
  const float* Wlin  = (const float*)d_in[20];
  const float* blin  = (const float*)d_in[21];
  const int* eind    = (const int*)d_in[22];
  const int* srcp    = eind;
  const int* dstp    = eind + N_EDGESC;
  const int* batch   = (const int*)d_in[23];
  float* out = (float*)d_out;

  char* ws=(char*)d_ws;
  size_t o=0;
  auto alloc=[&](size_t bytes)->void*{ void* p=ws+o; o=(o+bytes+255)&~(size_t)255; return p; };
  u16* hb   =(u16*)alloc((size_t)N_NODESC*HC*2);           // permuted bf16 h
  u16* Ahi =(u16*)alloc((size_t)N_NODESC*HC*2);            // agg bf16 out (next GEMM A)
  u16* Axhi=(u16*)alloc((size_t)N_NODESC*64*2);            // converted x (KP=64)
  u16* Axlo=(u16*)alloc((size_t)N_NODESC*64*2);
  const int WB0=0, WB1=HC*64, WB2=WB1+HC*HC;               // packed Bt offsets
  u16* Bthi3=(u16*)alloc((size_t)(WB2+HC*HC)*2);
  u16* Btlo3=(u16*)alloc((size_t)(WB2+HC*HC)*2);
  float* al   =(float*)alloc((size_t)N_NODESC*5*4);
  float* ar   =(float*)alloc((size_t)N_NODESC*5*4);
  float* qn   =(float*)alloc((size_t)N_NODESC*5*4);
  float* ael3 =(float*)alloc((size_t)3*N_NODESC*5*4);
  float* aeC3 =(float*)alloc((size_t)3*N_EDGESC*5*4);
  float* wE   =(float*)alloc((size_t)N_EDGESC*5*4);
  float* lattr=(float*)alloc((size_t)N_NODESC*10*4);
  float* eattrC=(float*)alloc((size_t)N_EDGESC*10*4);
  float* ve3  =(float*)alloc(256*4);
  float* cbv  =(float*)alloc(64*4);
  float* pnode=(float*)alloc((size_t)N_NODESC*4);
  int* cntI   =(int*)alloc((size_t)N_NODESC*4);
  int* rptr   =(int*)alloc((size_t)N_NODESC*4);
  int* pos    =(int*)alloc((size_t)N_NODESC*4);
  int* eidx   =(int*)alloc((size_t)N_EDGESC*4);
  int* srcE   =(int*)alloc((size_t)N_EDGESC*4);
  int* dstC   =(int*)alloc((size_t)N_EDGESC*4);

  hipMemsetAsync(cntI,0,(size_t)N_NODESC*4,stream);

  k_count<<<(N_EDGESC+255)/256,256,0,stream>>>(dstp,cntI);
  k_scan<<<1,1024,0,stream>>>(cntI,rptr,pos);
  k_scatter<<<(N_EDGESC+255)/256,256,0,stream>>>(dstp,pos,eidx,dstC);
  k_csr_edges<<<(N_EDGESC+255)/256,256,0,stream>>>(eidx,srcp,eattr,srcE,eattrC);
  k_loop_attr<<<(N_NODESC+3)/4,256,0,stream>>>(eattrC,rptr,cntI,lattr);
  k_conv_x<<<(N_NODESC*64+255)/256,256,0,stream>>>(x,Axhi,Axlo);
  k_ve3<<<1,256,0,stream>>>(We[0],aedge[0],We[1],aedge[1],We[2],aedge[2],ve3);
  k_cb<<<1,64,0,stream>>>(bias[2],Wlin,cbv);
  {
    int tot=WB2+HC*HC;
    k_conv_w3<<<(tot+255)/256,256,0,stream>>>(W[0],W[1],W[2],Bthi3,Btlo3);
  }
  {
    const int NEDGET=N_EDGESC+N_NODESC*5;
    k_edge_terms3<<<(3*NEDGET+255)/256,256,0,stream>>>(eattrC,lattr,ve3,aeC3,ael3);
  }

  const int NBLK=5*((N_NODESC+127)/128);
  const int WBo[3]={WB0,WB1,WB2};
  for(int L=0;L<3;L++){
    int KP = (L==0)? 64 : HC;
    const float* aeL = aeC3 + (size_t)L*N_EDGESC*5;
    const float* aelL= ael3 + (size_t)L*N_NODESC*5;
    if(L==0){
      k_gemm_fused<3,true,false><<<NBLK,256,0,stream>>>(Axhi,Axlo,Bthi3+WBo[L],Btlo3+WBo[L],
          asrc[L],adst[L],Wlin,hb,al,ar,qn,N_NODESC,KP,NBLK);
      k_edgew<<<(N_EDGESC+255)/256,256,0,stream>>>(srcE,dstC,al,ar,aeL,wE);
      k_agg<<<(N_NODESC+3)/4,256,0,stream>>>(hb,srcE,rptr,cntI,al,ar,aelL,wE,bias[L],Ahi);
    }else if(L==1){
      k_gemm_fused<1,true,false><<<NBLK,256,0,stream>>>(Ahi,(const u16*)nullptr,Bthi3+WBo[L],(const u16*)nullptr,
          asrc[L],adst[L],Wlin,hb,al,ar,qn,N_NODESC,KP,NBLK);
      k_edgew<<<(N_EDGESC+255)/256,256,0,stream>>>(srcE,dstC,al,ar,aeL,wE);
      k_agg<<<(N_NODESC+3)/4,256,0,stream>>>(hb,srcE,rptr,cntI,al,ar,aelL,wE,bias[L],Ahi);
    }else{
      k_gemm_fused<1,false,true><<<NBLK,256,0,stream>>>(Ahi,(const u16*)nullptr,Bthi3+WBo[L],(const u16*)nullptr,
          asrc[L],adst[L],Wlin,hb,al,ar,qn,N_NODESC,KP,NBLK);
      k_agg_last<<<(N_NODESC+15)/16,256,0,stream>>>(qn,srcE,rptr,cntI,al,ar,aelL,aeL,cbv,pnode);
    }
  }
  k_graphout<<<(NGRAPH+3)/4,256,0,stream>>>(pnode,batch,blin,out);
}